// Round 7
// baseline (190.045 us; speedup 1.0000x reference)
//
#include <hip/hip_runtime.h>

typedef __bf16 bf16_t;
typedef __attribute__((ext_vector_type(8))) __bf16 bf16x8;
typedef __attribute__((ext_vector_type(4))) __bf16 bf16x4;
typedef __attribute__((ext_vector_type(4))) float f32x4;
typedef __attribute__((ext_vector_type(16))) float f32x16;
typedef __attribute__((ext_vector_type(2))) unsigned uint2v;

#define MFMA16(a, b, c) __builtin_amdgcn_mfma_f32_16x16x32_bf16((a), (b), (c), 0, 0, 0)
#define MFMA32(a, b, c) __builtin_amdgcn_mfma_f32_32x32x16_bf16((a), (b), (c), 0, 0, 0)
#define LOG2E 1.44269504088896f

// Async global->LDS 16B copy. LDS dest is the WAVE-UNIFORM base; HW places
// lane i's 16B at base + 16*i. gptr is per-lane.
__device__ __forceinline__ void async16(const bf16_t* g, bf16_t* l) {
    __builtin_amdgcn_global_load_lds(
        (const __attribute__((address_space(1))) unsigned int*)g,
        (__attribute__((address_space(3))) unsigned int*)l, 16, 0, 0);
}

__device__ __forceinline__ unsigned pack2(float a, float b) {
    union { bf16_t e[2]; unsigned u; } x;
    x.e[0] = (bf16_t)a; x.e[1] = (bf16_t)b;
    return x.u;
}

// lane[i]<->lane[i+32] half exchange on the VALU pipe (v_permlane32_swap_b32).
__device__ __forceinline__ void pl32swap(unsigned& a, unsigned& b) {
    uint2v r = __builtin_amdgcn_permlane32_swap(a, b, false, false);
    a = r[0]; b = r[1];
}

// Raw workgroup barrier WITHOUT the vmcnt(0) drain of __syncthreads.
// Used only where no LDS data hazard crosses it (pure phase lockstep);
// compiler-level memory clobbers stop reordering of LDS ops across it.
__device__ __forceinline__ void pbar() {
    asm volatile("" ::: "memory");
    __builtin_amdgcn_s_barrier();
    asm volatile("" ::: "memory");
}

// ---------------------------------------------------------------------------
// Fused fp32 -> bf16 conversion of x / W_in / W_out into contiguous ws region.
// ---------------------------------------------------------------------------
__global__ __launch_bounds__(256) void conv3(
    const float* __restrict__ s0, const float* __restrict__ s1,
    const float* __restrict__ s2, bf16_t* __restrict__ dst,
    int n0, int n1)
{
    const int i = (blockIdx.x * 256 + threadIdx.x) * 8;
    const float* src;
    int off;
    if (i < n0)           { src = s0; off = 0; }
    else if (i < n0 + n1) { src = s1; off = n0; }
    else                  { src = s2; off = n0 + n1; }
    const float4 a = *reinterpret_cast<const float4*>(src + i - off);
    const float4 b = *reinterpret_cast<const float4*>(src + i - off + 4);
    bf16x8 o;
    o[0] = (bf16_t)a.x; o[1] = (bf16_t)a.y; o[2] = (bf16_t)a.z; o[3] = (bf16_t)a.w;
    o[4] = (bf16_t)b.x; o[5] = (bf16_t)b.y; o[6] = (bf16_t)b.z; o[7] = (bf16_t)b.w;
    *reinterpret_cast<bf16x8*>(dst + i) = o;
}

// ---------------------------------------------------------------------------
// QKV projection GEMM -- 256x256 tile, BK=64, 8 waves, 4-phase quadrant
// schedule (T2 swizzle + T3 phasing + T5 setprio; m198/m201-class template).
// qkv[m][f] = X[m][:] . W[f][:] + bias[f], f in [0,3072), m in [0,4096).
//
// LDS 128 KB: 2 dbuf x (A 256x64 + B 256x64) bf16. 1 block/CU, 2 waves/SIMD.
// Per K-step (64): step-boundary __syncthreads (its vmcnt(0) drains staging
// issued a FULL STEP earlier -> ~free), then issue all 8 async16 for step
// s+1 into buf[set^1] (readers of that buffer finished before the barrier),
// then 4 phases: {ds_read new frags; setprio(1); 16 MFMA; setprio(0); raw
// s_barrier}. Quadrant order Q(0,0),(1,0),(1,1),(0,1) -- A0 frags stay live
// so phase 4 needs no reads. Chunk-XOR c^(r&7) on BOTH staging source and
// frag reads (involution; 128B rows): frag reads land 8 lanes/slot on
// distinct rows = uniform 8-deep = the b128 floor (bank-balanced).
// Accumulation = ascending-k MFMA16 pairs -> bit-identical to the 2-phase
// BK=32 kernel it replaces.
// Epilogue: bias + qscale (f<1024); V third (f>=2048) written TRANSPOSED to
// vT[bh][d][s] (fused vtrans, verified in R6).
// Grid 192 = 12(f) x 16(m), XCD swizzle on m: x8=id&7, mb=((k&1)*8+x8)*256,
// fb=(k>>1)*256.
// ---------------------------------------------------------------------------
__global__ __launch_bounds__(512, 2) void gemm_qkv(
    const bf16_t* __restrict__ W, const bf16_t* __restrict__ X,
    const float* __restrict__ bias, bf16_t* __restrict__ qkv,
    bf16_t* __restrict__ vtp)
{
    constexpr int K = 1024;
    constexpr int NSTEP = K / 64;        // 16

    __shared__ bf16_t lds[2][32768];     // [set][A 16384 | B 16384]

    const int tid  = threadIdx.x;        // 0..511
    const int lane = tid & 63;
    const int wv   = tid >> 6;           // 0..7
    const int wm   = wv >> 2;            // f-half of the tile (0..1)
    const int wn   = wv & 3;             // m-quarter (0..3)
    const int l15  = lane & 15;
    const int qd   = lane >> 4;

    const int id = blockIdx.x;           // 0..191
    const int x8 = id & 7, k = id >> 3;  // k 0..23
    const int mb = ((k & 1) * 8 + x8) * 256;
    const int fb = (k >> 1) * 256;

    f32x4 acc[8][4] = {};                // [i: f frag 0..7][j: m frag 0..3]

    auto stage = [&](int set, int k0) {
        bf16_t* Ab = lds[set];
        bf16_t* Bb = lds[set] + 16384;
#pragma unroll
        for (int h = 0; h < 2; h++) {    // 128-row half-tiles
#pragma unroll
            for (int t = 0; t < 2; t++) {
                const int p = (wv * 2 + t) * 64 + lane;   // 0..1023
                const int r = p >> 3;                     // 0..127
                const int c = (p & 7) ^ (r & 7);          // global chunk
                async16(W + (size_t)(fb + h * 128 + r) * K + k0 + c * 8,
                        Ab + h * 8192 + (wv * 2 + t) * 512);
                async16(X + (size_t)(mb + h * 128 + r) * K + k0 + c * 8,
                        Bb + h * 8192 + (wv * 2 + t) * 512);
            }
        }
    };

    stage(0, 0);                         // prologue: step 0 -> buf 0
    for (int s = 0; s < NSTEP; s++) {
        const int set = s & 1;
        __syncthreads();                 // drains buf[set] staging (old); fence
        if (s + 1 < NSTEP) stage(set ^ 1, (s + 1) * 64);

        const bf16_t* Ab = lds[set];
        const bf16_t* Bb = lds[set] + 16384;

        bf16x8 a0[4][2], a1[4][2], b0[2][2], b1[2][2];

        // ---- phase 1: Q(0,0) -- load a0 (8), b0 (4) ----
#pragma unroll
        for (int i = 0; i < 4; i++) {
            const int r = wm * 128 + i * 16 + l15;
            a0[i][0] = *reinterpret_cast<const bf16x8*>(
                Ab + r * 64 + ((qd ^ (r & 7)) * 8));
            a0[i][1] = *reinterpret_cast<const bf16x8*>(
                Ab + r * 64 + (((4 + qd) ^ (r & 7)) * 8));
        }
#pragma unroll
        for (int j = 0; j < 2; j++) {
            const int r = wn * 64 + j * 16 + l15;
            b0[j][0] = *reinterpret_cast<const bf16x8*>(
                Bb + r * 64 + ((qd ^ (r & 7)) * 8));
            b0[j][1] = *reinterpret_cast<const bf16x8*>(
                Bb + r * 64 + (((4 + qd) ^ (r & 7)) * 8));
        }
        __builtin_amdgcn_s_setprio(1);
#pragma unroll
        for (int i = 0; i < 4; i++)
#pragma unroll
            for (int j = 0; j < 2; j++) {
                acc[i][j] = MFMA16(a0[i][0], b0[j][0], acc[i][j]);
                acc[i][j] = MFMA16(a0[i][1], b0[j][1], acc[i][j]);
            }
        __builtin_amdgcn_s_setprio(0);
        pbar();

        // ---- phase 2: Q(1,0) -- load a1 (8), reuse b0 ----
#pragma unroll
        for (int i = 0; i < 4; i++) {
            const int r = wm * 128 + (i + 4) * 16 + l15;
            a1[i][0] = *reinterpret_cast<const bf16x8*>(
                Ab + r * 64 + ((qd ^ (r & 7)) * 8));
            a1[i][1] = *reinterpret_cast<const bf16x8*>(
                Ab + r * 64 + (((4 + qd) ^ (r & 7)) * 8));
        }
        __builtin_amdgcn_s_setprio(1);
#pragma unroll
        for (int i = 0; i < 4; i++)
#pragma unroll
            for (int j = 0; j < 2; j++) {
                acc[i + 4][j] = MFMA16(a1[i][0], b0[j][0], acc[i + 4][j]);
                acc[i + 4][j] = MFMA16(a1[i][1], b0[j][1], acc[i + 4][j]);
            }
        __builtin_amdgcn_s_setprio(0);
        pbar();

        // ---- phase 3: Q(1,1) -- load b1 (4), reuse a1 ----
#pragma unroll
        for (int j = 0; j < 2; j++) {
            const int r = wn * 64 + (j + 2) * 16 + l15;
            b1[j][0] = *reinterpret_cast<const bf16x8*>(
                Bb + r * 64 + ((qd ^ (r & 7)) * 8));
            b1[j][1] = *reinterpret_cast<const bf16x8*>(
                Bb + r * 64 + (((4 + qd) ^ (r & 7)) * 8));
        }
        __builtin_amdgcn_s_setprio(1);
#pragma unroll
        for (int i = 0; i < 4; i++)
#pragma unroll
            for (int j = 0; j < 2; j++) {
                acc[i + 4][j + 2] = MFMA16(a1[i][0], b1[j][0], acc[i + 4][j + 2]);
                acc[i + 4][j + 2] = MFMA16(a1[i][1], b1[j][1], acc[i + 4][j + 2]);
            }
        __builtin_amdgcn_s_setprio(0);
        pbar();

        // ---- phase 4: Q(0,1) -- reuse a0, b1 (no reads) ----
        __builtin_amdgcn_s_setprio(1);
#pragma unroll
        for (int i = 0; i < 4; i++)
#pragma unroll
            for (int j = 0; j < 2; j++) {
                acc[i][j + 2] = MFMA16(a0[i][0], b1[j][0], acc[i][j + 2]);
                acc[i][j + 2] = MFMA16(a0[i][1], b1[j][1], acc[i][j + 2]);
            }
        __builtin_amdgcn_s_setprio(0);
        // step-boundary __syncthreads at loop top separates phase 4 from
        // the next step's staging overwrite of buf[set^1].
    }

    // ---- epilogue: bias + scale; V third transposed into vT ----
    const float scale = (fb < 1024) ? 0.125f * LOG2E : 1.0f;
    const bool vblk = (fb >= 2048);
#pragma unroll
    for (int i = 0; i < 8; i++) {
        const int f0 = fb + wm * 128 + i * 16 + qd * 4;
        float bs[4];
#pragma unroll
        for (int r = 0; r < 4; r++) bs[r] = bias[f0 + r];
#pragma unroll
        for (int j = 0; j < 4; j++) {
            const int m = mb + wn * 64 + j * 16 + l15;
            if (vblk) {
                const int sIdx = m >> 1;          // B = 2 row interleave
                const int b2   = (m & 1) << 4;    // b*16
#pragma unroll
                for (int r = 0; r < 4; r++) {
                    const int fv = f0 + r - 2048;
                    vtp[(size_t)((b2 + (fv >> 6)) * 64 + (fv & 63)) * 2048 + sIdx] =
                        (bf16_t)(acc[i][j][r] + bs[r]);
                }
            } else {
                bf16x4 o;
#pragma unroll
                for (int r = 0; r < 4; r++)
                    o[r] = (bf16_t)((acc[i][j][r] + bs[r]) * scale);
                *reinterpret_cast<bf16x4*>(qkv + (size_t)m * 3072 + f0) = o;
            }
        }
    }
}

// ---------------------------------------------------------------------------
// NT GEMM (out-proj), double-buffered BK=32, one barrier per K-iter. Tile
// 128(f) x MT(m). 1D grid with XCD swizzle. MT=64 -> 512 blocks (2/CU).
// ---------------------------------------------------------------------------
template <int MT, bool F32OUT>
__global__ __launch_bounds__(256, 3) void gemm_nt_lds(
    const bf16_t* __restrict__ W, const bf16_t* __restrict__ X,
    const float* __restrict__ bias, void* __restrict__ Cv,
    int N, int K, int fpx)
{
    constexpr int NJ = MT / 32;
    __shared__ bf16_t As[2][128 * 32];
    __shared__ bf16_t Bs[2][MT * 32];

    const int lane = threadIdx.x & 63;
    const int wv   = threadIdx.x >> 6;
    const int l15  = lane & 15;
    const int qd   = lane >> 4;

    const int id = blockIdx.x;
    const int x8 = id & 7, k = id >> 3;
    const int fb = ((k % fpx) * 8 + x8) * 128;
    const int mb = (k / fpx) * MT;
    const int fw = (wv & 1) * 64;
    const int mw = (wv >> 1) * (MT / 2);

    f32x4 acc[4][NJ] = {};

    auto stage = [&](int set, int k0) {
#pragma unroll
        for (int t = 0; t < 2; t++) {
            const int p = (wv * 2 + t) * 64 + lane;
            const int r = p >> 2, cl = (p & 3) ^ (r & 3);
            async16(W + (size_t)(fb + r) * K + k0 + cl * 8,
                    &As[set][(wv * 2 + t) * 512]);
        }
#pragma unroll
        for (int t = 0; t < MT / 64; t++) {
            const int p = (wv * (MT / 64) + t) * 64 + lane;
            const int r = p >> 2, cl = (p & 3) ^ (r & 3);
            async16(X + (size_t)(mb + r) * K + k0 + cl * 8,
                    &Bs[set][(wv * (MT / 64) + t) * 512]);
        }
    };

    stage(0, 0);
    int set = 0;
    for (int k0 = 0; k0 < K; k0 += 32) {
        __syncthreads();
        if (k0 + 32 < K) stage(set ^ 1, k0 + 32);

        const int s3 = l15 & 3;
        bf16x8 a[4], bb[NJ];
#pragma unroll
        for (int i = 0; i < 4; i++)
            a[i] = *reinterpret_cast<const bf16x8*>(
                &As[set][(fw + i * 16 + l15) * 32 + ((qd ^ s3) * 8)]);
#pragma unroll
        for (int j = 0; j < NJ; j++)
            bb[j] = *reinterpret_cast<const bf16x8*>(
                &Bs[set][(mw + j * 16 + l15) * 32 + ((qd ^ s3) * 8)]);
#pragma unroll
        for (int i = 0; i < 4; i++)
#pragma unroll
            for (int j = 0; j < NJ; j++)
                acc[i][j] = MFMA16(a[i], bb[j], acc[i][j]);
        set ^= 1;
    }

#pragma unroll
    for (int i = 0; i < 4; i++) {
        const int f0 = fb + fw + i * 16 + qd * 4;
        float bs[4];
#pragma unroll
        for (int r = 0; r < 4; r++) bs[r] = bias[f0 + r];
#pragma unroll
        for (int j = 0; j < NJ; j++) {
            const int m = mb + mw + j * 16 + l15;
            if (F32OUT) {
                float4 o;
                o.x = acc[i][j][0] + bs[0];
                o.y = acc[i][j][1] + bs[1];
                o.z = acc[i][j][2] + bs[2];
                o.w = acc[i][j][3] + bs[3];
                *reinterpret_cast<float4*>((float*)Cv + (size_t)m * N + f0) = o;
            } else {
                bf16x4 o;
#pragma unroll
                for (int r = 0; r < 4; r++)
                    o[r] = (bf16_t)(acc[i][j][r] + bs[r]);
                *reinterpret_cast<bf16x4*>((bf16_t*)Cv + (size_t)m * N + f0) = o;
            }
        }
    }
}

// ---------------------------------------------------------------------------
// Flash attention with IN-BLOCK KV-split x2 (exact R2 kernel, verified
// 54.0 us). Block = 4 waves / 128 q. Grid 32 bh x 16 = 512 blocks, 2/CU.
// ---------------------------------------------------------------------------
__global__ __launch_bounds__(256, 2) void flash_attn(
    const bf16_t* __restrict__ qkv, const bf16_t* __restrict__ vT,
    bf16_t* __restrict__ attn, int S, int B)
{
    const int E3 = 3072, E = 1024;
    const int bh = blockIdx.x, b = bh >> 4, h = bh & 15;
    const int tid = threadIdx.x, lane = tid & 63, wv = tid >> 6;  // 0..3
    const int qw = wv & 1;               // q sub-block (64 q each)
    const int pr = wv >> 1;              // KV half
    const int l31 = lane & 31, half = lane >> 5;

    __shared__ bf16_t Kt[2][2][64 * 64];  // [pair][set]; chunk c at c^(r&7)
    __shared__ bf16_t Vt[2][2][64 * 64];  // [pair][set]; row d, chunk c at c^(d&7)
    __shared__ float  lsh[2][64];

    const int q0 = blockIdx.y * 128 + qw * 64;

    bf16x8 qf[2][4];                     // Q[q][k = ks*16 + half*8 + j]
#pragma unroll
    for (int qt = 0; qt < 2; qt++) {
        const bf16_t* qp = qkv + (size_t)((q0 + qt * 32 + l31) * B + b) * E3 + h * 64;
#pragma unroll
        for (int ks = 0; ks < 4; ks++)
            qf[qt][ks] = *reinterpret_cast<const bf16x8*>(qp + ks * 16 + half * 8);
    }

    f32x16 oacc[2][2] = {};              // [qt][d-tile]; row=d col=q
    float lrun[2] = {0.0f, 0.0f};

    auto stage = [&](int set, int kv) {
#pragma unroll
        for (int t = 0; t < 4; t++) {
            const int p = (qw * 4 + t) * 64 + lane;     // phys chunk 0..511
            const int r = p >> 3, cl = (p & 7) ^ (r & 7);
            async16(qkv + (size_t)((kv + r) * B + b) * E3 + E + h * 64 + cl * 8,
                    &Kt[pr][set][(qw * 4 + t) * 512]);
            async16(vT + (size_t)(bh * 64 + r) * 2048 + kv + cl * 8,
                    &Vt[pr][set][(qw * 4 + t) * 512]);
        }
    };

    const int kvbase = pr * (S / 2);
    const int NIT = S / 128;             // 16 iters of 64 per pair

    stage(0, kvbase);
    int set = 0;
    for (int it = 0; it < NIT; it++) {
        __syncthreads();                 // buf[set] ready; buf[set^1] free
        if (it + 1 < NIT) stage(set ^ 1, kvbase + (it + 1) * 64);

        const bf16_t* K_ = Kt[pr][set];
        const bf16_t* V_ = Vt[pr][set];

        union PF { unsigned u[4]; bf16x8 v; };
        PF pf[2][4];
#pragma unroll
        for (int nt = 0; nt < 2; nt++) {
            const int r = nt * 32 + l31;
            const int r7 = r & 7;
            bf16x8 kf[4];
#pragma unroll
            for (int ks = 0; ks < 4; ks++)
                kf[ks] = *reinterpret_cast<const bf16x8*>(
                    K_ + r * 64 + (((ks * 2 + half) ^ r7) * 8));
#pragma unroll
            for (int qt = 0; qt < 2; qt++) {
                f32x16 st = {};
                __builtin_amdgcn_s_setprio(1);
#pragma unroll
                for (int ks = 0; ks < 4; ks++)
                    st = MFMA32(kf[ks], qf[qt][ks], st);
                __builtin_amdgcn_s_setprio(0);
                float ls = 0.0f;
                unsigned q8[8];
#pragma unroll
                for (int g = 0; g < 4; g++) {
                    const float p0 = __builtin_amdgcn_exp2f(st[4 * g]);
                    const float p1 = __builtin_amdgcn_exp2f(st[4 * g + 1]);
                    const float p2 = __builtin_amdgcn_exp2f(st[4 * g + 2]);
                    const float p3 = __builtin_amdgcn_exp2f(st[4 * g + 3]);
                    ls += (p0 + p1) + (p2 + p3);
                    q8[2 * g]     = pack2(p0, p1);
                    q8[2 * g + 1] = pack2(p2, p3);
                }
                lrun[qt] += ls;
                pl32swap(q8[0], q8[2]); pl32swap(q8[1], q8[3]);
                pl32swap(q8[4], q8[6]); pl32swap(q8[5], q8[7]);
                pf[qt][nt * 2 + 0].u[0] = q8[0]; pf[qt][nt * 2 + 0].u[1] = q8[1];
                pf[qt][nt * 2 + 0].u[2] = q8[2]; pf[qt][nt * 2 + 0].u[3] = q8[3];
                pf[qt][nt * 2 + 1].u[0] = q8[4]; pf[qt][nt * 2 + 1].u[1] = q8[5];
                pf[qt][nt * 2 + 1].u[2] = q8[6]; pf[qt][nt * 2 + 1].u[3] = q8[7];
            }
        }
        __builtin_amdgcn_s_setprio(1);
#pragma unroll
        for (int kn = 0; kn < 4; kn++)
#pragma unroll
            for (int dt = 0; dt < 2; dt++) {
                const int d = dt * 32 + l31;
                bf16x8 vf = *reinterpret_cast<const bf16x8*>(
                    V_ + d * 64 + (((kn * 2 + half) ^ (d & 7)) * 8));
                oacc[0][dt] = MFMA32(vf, pf[0][kn].v, oacc[0][dt]);
                oacc[1][dt] = MFMA32(vf, pf[1][kn].v, oacc[1][dt]);
            }
        __builtin_amdgcn_s_setprio(0);
        set ^= 1;
    }

    // --- Epilogue: merge the two KV halves through LDS, normalize, store ---
    __syncthreads();                     // all K/V reads done; LDS reusable
    float lr[2];
#pragma unroll
    for (int qt = 0; qt < 2; qt++) lr[qt] = lrun[qt] + __shfl_xor(lrun[qt], 32);

    // fp32 scratch overlays Kt (32 KB = 2 regions x 64q x 64d), d-major
    float* fo = reinterpret_cast<float*>(&Kt[0][0][0]) + qw * 4096;

    if (pr == 1) {
#pragma unroll
        for (int qt = 0; qt < 2; qt++) {
            const int ql = qt * 32 + l31;
            lsh[qw][ql] = lr[qt];        // both halves write same value
#pragma unroll
            for (int dt = 0; dt < 2; dt++)
#pragma unroll
                for (int g = 0; g < 4; g++)
#pragma unroll
                    for (int r = 0; r < 4; r++) {
                        const int d = dt * 32 + g * 8 + half * 4 + r;
                        fo[d * 64 + ql] = oacc[qt][dt][4 * g + r];
                    }
        }
    }
    __syncthreads();
    if (pr == 0) {
#pragma unroll
        for (int qt = 0; qt < 2; qt++) {
            const int ql = qt * 32 + l31;
            const float inv = 1.0f / (lr[qt] + lsh[qw][ql]);
            const int qrow = q0 + qt * 32 + l31;
#pragma unroll
            for (int dt = 0; dt < 2; dt++)
#pragma unroll
                for (int g = 0; g < 4; g++) {
                    bf16x4 o;
#pragma unroll
                    for (int r = 0; r < 4; r++) {
                        const int d = dt * 32 + g * 8 + half * 4 + r;
                        o[r] = (bf16_t)((oacc[qt][dt][4 * g + r] + fo[d * 64 + ql]) * inv);
                    }
                    *reinterpret_cast<bf16x4*>(attn + (size_t)(qrow * B + b) * E +
                                               h * 64 + dt * 32 + g * 8 + half * 4) = o;
                }
        }
    }
}

extern "C" void kernel_launch(void* const* d_in, const int* in_sizes, int n_in,
                              void* d_out, int out_size, void* d_ws, size_t ws_size,
                              hipStream_t stream) {
    const float* x  = (const float*)d_in[0];
    const float* wi = (const float*)d_in[1];
    const float* bi = (const float*)d_in[2];
    const float* wo = (const float*)d_in[3];
    const float* bo = (const float*)d_in[4];
    float* out = (float*)d_out;

    const int S = 2048, B = 2, E = 1024;
    const int M = S * B;

    // Workspace layout:
    //   xb [M,1024] bf16  -- X in bf16; dead after QKV GEMM
    //   wib[3072,1024]    -- W_in bf16
    //   wob[1024,1024]    -- W_out bf16
    //   qkv[M,3072]       -- Q,K written by GEMM; V third left unwritten
    //   vT [32][64][2048] -- V transposed, written by the GEMM epilogue
    //   attn = xb overlay -- flash output (xb dead by then)
    bf16_t* xb   = (bf16_t*)d_ws;
    bf16_t* wib  = xb  + (size_t)M * E;
    bf16_t* wob  = wib + (size_t)3 * E * E;
    bf16_t* qkv  = wob + (size_t)E * E;
    bf16_t* vT   = qkv + (size_t)M * 3 * E;
    bf16_t* attn = xb;

    // 0) fused fp32 -> bf16
    const int n0 = M * E, n1 = 3 * E * E, n2 = E * E;
    conv3<<<(n0 + n1 + n2) / 8 / 256, 256, 0, stream>>>(x, wi, wo, xb, n0, n1);

    // 1) QKV projection: 256^2 4-phase template; V third transposed into vT;
    //    (1/8)*LOG2E folded into q cols. Grid 192 = 12(f) x 16(m).
    gemm_qkv<<<192, 512, 0, stream>>>(wib, xb, bi, qkv, vT);

    // 2) Flash attention (exact R2 kernel; attn overlays dead xb)
    flash_attn<<<dim3(B * 16, S / 128), 256, 0, stream>>>(qkv, vT, attn, S, B);

    // 3) Output projection, MT=64 (512 blocks = 2/CU)
    gemm_nt_lds<64, true><<<(E / 128) * (M / 64), 256, 0, stream>>>(
        wob, attn, bo, out, E, E, 1);
}

// Round 8
// 183.591 us; speedup vs baseline: 1.0352x; 1.0352x over previous
//
#include <hip/hip_runtime.h>

typedef __bf16 bf16_t;
typedef __attribute__((ext_vector_type(8))) __bf16 bf16x8;
typedef __attribute__((ext_vector_type(4))) __bf16 bf16x4;
typedef __attribute__((ext_vector_type(4))) float f32x4;
typedef __attribute__((ext_vector_type(16))) float f32x16;
typedef __attribute__((ext_vector_type(2))) unsigned uint2v;

#define MFMA16(a, b, c) __builtin_amdgcn_mfma_f32_16x16x32_bf16((a), (b), (c), 0, 0, 0)
#define MFMA32(a, b, c) __builtin_amdgcn_mfma_f32_32x32x16_bf16((a), (b), (c), 0, 0, 0)
#define LOG2E 1.44269504088896f

// Async global->LDS 16B copy. LDS dest is the WAVE-UNIFORM base; HW places
// lane i's 16B at base + 16*i. gptr is per-lane.
__device__ __forceinline__ void async16(const bf16_t* g, bf16_t* l) {
    __builtin_amdgcn_global_load_lds(
        (const __attribute__((address_space(1))) unsigned int*)g,
        (__attribute__((address_space(3))) unsigned int*)l, 16, 0, 0);
}

__device__ __forceinline__ unsigned pack2(float a, float b) {
    union { bf16_t e[2]; unsigned u; } x;
    x.e[0] = (bf16_t)a; x.e[1] = (bf16_t)b;
    return x.u;
}

// lane[i]<->lane[i+32] half exchange on the VALU pipe (v_permlane32_swap_b32).
__device__ __forceinline__ void pl32swap(unsigned& a, unsigned& b) {
    uint2v r = __builtin_amdgcn_permlane32_swap(a, b, false, false);
    a = r[0]; b = r[1];
}

// Raw workgroup barrier WITHOUT the vmcnt(0) drain of __syncthreads.
// Used only where no LDS data hazard crosses it (pure phase lockstep);
// compiler-level memory clobbers stop reordering of LDS ops across it.
__device__ __forceinline__ void pbar() {
    asm volatile("" ::: "memory");
    __builtin_amdgcn_s_barrier();
    asm volatile("" ::: "memory");
}

// ---------------------------------------------------------------------------
// Fused fp32 -> bf16 conversion of x / W_in / W_out into contiguous ws region.
// ---------------------------------------------------------------------------
__global__ __launch_bounds__(256) void conv3(
    const float* __restrict__ s0, const float* __restrict__ s1,
    const float* __restrict__ s2, bf16_t* __restrict__ dst,
    int n0, int n1)
{
    const int i = (blockIdx.x * 256 + threadIdx.x) * 8;
    const float* src;
    int off;
    if (i < n0)           { src = s0; off = 0; }
    else if (i < n0 + n1) { src = s1; off = n0; }
    else                  { src = s2; off = n0 + n1; }
    const float4 a = *reinterpret_cast<const float4*>(src + i - off);
    const float4 b = *reinterpret_cast<const float4*>(src + i - off + 4);
    bf16x8 o;
    o[0] = (bf16_t)a.x; o[1] = (bf16_t)a.y; o[2] = (bf16_t)a.z; o[3] = (bf16_t)a.w;
    o[4] = (bf16_t)b.x; o[5] = (bf16_t)b.y; o[6] = (bf16_t)b.z; o[7] = (bf16_t)b.w;
    *reinterpret_cast<bf16x8*>(dst + i) = o;
}

// ---------------------------------------------------------------------------
// QKV projection GEMM -- 192(f) x 256(m) tile, BK=64, 8 waves, 4-phase
// quadrant schedule. R7 measured the 4-phase structure at +33% per-CU vs the
// 2-phase 128^2 baseline but wasted it on a 192-block grid (75% of CUs);
// this round's only change is geometry: 16 f-tiles x 16 m-tiles = 256 blocks
// = exactly 1 block/CU (100% subscription).
// LDS 112 KB: 2 dbuf x (A 192x64 + B 256x64) bf16. 2 waves/SIMD.
// Per K-step: __syncthreads (drains staging issued a full step earlier ->
// cheap), issue 7 async16 for step s+1, then 4 phases {ds_read frags;
// setprio(1); 12 MFMA; setprio(0); pbar()}. Quadrants: a-halves (3x16 f
// rows) x b-halves (2x16 m rows), order (0,0),(1,0),(1,1),(0,1) so phase 4
// needs no reads. Chunk-XOR c^(r&7) on BOTH staging source and frag reads.
// k-order per output element unchanged (chunk qd then 4+qd, ascending
// steps) -> bit-identical output vs R6/R7.
// Epilogue: per-i scale/vblk selection (16-aligned groups; 1024/2048
// boundaries are multiples of 16 so the 192-tile straddling is exact);
// V third (f>=2048) written transposed into vT (fused vtrans, R6-verified).
// Grid 256: x8=id&7, k=id>>3 (0..31): mb=((k&1)*8+x8)*256, fb=(k>>1)*192.
// ---------------------------------------------------------------------------
__global__ __launch_bounds__(512, 2) void gemm_qkv(
    const bf16_t* __restrict__ W, const bf16_t* __restrict__ X,
    const float* __restrict__ bias, bf16_t* __restrict__ qkv,
    bf16_t* __restrict__ vtp)
{
    constexpr int K = 1024;
    constexpr int NSTEP = K / 64;        // 16
    constexpr int AELEM = 192 * 64;      // 12288 elems = 24 KB
    constexpr int BELEM = 256 * 64;      // 16384 elems = 32 KB

    __shared__ bf16_t lds[2][AELEM + BELEM];   // 112 KB total

    const int tid  = threadIdx.x;        // 0..511
    const int lane = tid & 63;
    const int wv   = tid >> 6;           // 0..7
    const int wm   = wv >> 2;            // f-half of 192 (96 rows each)
    const int wn   = wv & 3;             // m-quarter of 256 (64 rows each)
    const int l15  = lane & 15;
    const int qd   = lane >> 4;

    const int id = blockIdx.x;           // 0..255
    const int x8 = id & 7, k = id >> 3;  // k 0..31
    const int mb = ((k & 1) * 8 + x8) * 256;
    const int fb = (k >> 1) * 192;

    f32x4 acc[6][4] = {};                // [i: f frag 0..5][j: m frag 0..3]

    auto stage = [&](int set, int k0) {
        bf16_t* Ab = lds[set];
        bf16_t* Bb = lds[set] + AELEM;
#pragma unroll
        for (int t = 0; t < 3; t++) {    // A: 192 rows = 1536 chunks
            const int p = t * 512 + tid;
            const int r = p >> 3;
            const int c = (p & 7) ^ (r & 7);
            async16(W + (size_t)(fb + r) * K + k0 + c * 8,
                    Ab + (t * 512 + wv * 64) * 8);
        }
#pragma unroll
        for (int t = 0; t < 4; t++) {    // B: 256 rows = 2048 chunks
            const int p = t * 512 + tid;
            const int r = p >> 3;
            const int c = (p & 7) ^ (r & 7);
            async16(X + (size_t)(mb + r) * K + k0 + c * 8,
                    Bb + (t * 512 + wv * 64) * 8);
        }
    };

    stage(0, 0);                         // prologue: step 0 -> buf 0
    for (int s = 0; s < NSTEP; s++) {
        const int set = s & 1;
        __syncthreads();                 // buf[set] staging drained; fence
        if (s + 1 < NSTEP) stage(set ^ 1, (s + 1) * 64);

        const bf16_t* Ab = lds[set];
        const bf16_t* Bb = lds[set] + AELEM;

        bf16x8 a0[3][2], a1[3][2], b0[2][2], b1[2][2];

        // ---- phase 1: Q(0,0) -- load a0 (i=0..2), b0 (j=0..1) ----
#pragma unroll
        for (int i = 0; i < 3; i++) {
            const int r = wm * 96 + i * 16 + l15;
            a0[i][0] = *reinterpret_cast<const bf16x8*>(
                Ab + r * 64 + ((qd ^ (r & 7)) * 8));
            a0[i][1] = *reinterpret_cast<const bf16x8*>(
                Ab + r * 64 + (((4 + qd) ^ (r & 7)) * 8));
        }
#pragma unroll
        for (int j = 0; j < 2; j++) {
            const int r = wn * 64 + j * 16 + l15;
            b0[j][0] = *reinterpret_cast<const bf16x8*>(
                Bb + r * 64 + ((qd ^ (r & 7)) * 8));
            b0[j][1] = *reinterpret_cast<const bf16x8*>(
                Bb + r * 64 + (((4 + qd) ^ (r & 7)) * 8));
        }
        __builtin_amdgcn_s_setprio(1);
#pragma unroll
        for (int i = 0; i < 3; i++)
#pragma unroll
            for (int j = 0; j < 2; j++) {
                acc[i][j] = MFMA16(a0[i][0], b0[j][0], acc[i][j]);
                acc[i][j] = MFMA16(a0[i][1], b0[j][1], acc[i][j]);
            }
        __builtin_amdgcn_s_setprio(0);
        pbar();

        // ---- phase 2: Q(1,0) -- load a1 (i=3..5), reuse b0 ----
#pragma unroll
        for (int i = 0; i < 3; i++) {
            const int r = wm * 96 + (i + 3) * 16 + l15;
            a1[i][0] = *reinterpret_cast<const bf16x8*>(
                Ab + r * 64 + ((qd ^ (r & 7)) * 8));
            a1[i][1] = *reinterpret_cast<const bf16x8*>(
                Ab + r * 64 + (((4 + qd) ^ (r & 7)) * 8));
        }
        __builtin_amdgcn_s_setprio(1);
#pragma unroll
        for (int i = 0; i < 3; i++)
#pragma unroll
            for (int j = 0; j < 2; j++) {
                acc[i + 3][j] = MFMA16(a1[i][0], b0[j][0], acc[i + 3][j]);
                acc[i + 3][j] = MFMA16(a1[i][1], b0[j][1], acc[i + 3][j]);
            }
        __builtin_amdgcn_s_setprio(0);
        pbar();

        // ---- phase 3: Q(1,1) -- load b1 (j=2..3), reuse a1 ----
#pragma unroll
        for (int j = 0; j < 2; j++) {
            const int r = wn * 64 + (j + 2) * 16 + l15;
            b1[j][0] = *reinterpret_cast<const bf16x8*>(
                Bb + r * 64 + ((qd ^ (r & 7)) * 8));
            b1[j][1] = *reinterpret_cast<const bf16x8*>(
                Bb + r * 64 + (((4 + qd) ^ (r & 7)) * 8));
        }
        __builtin_amdgcn_s_setprio(1);
#pragma unroll
        for (int i = 0; i < 3; i++)
#pragma unroll
            for (int j = 0; j < 2; j++) {
                acc[i + 3][j + 2] = MFMA16(a1[i][0], b1[j][0], acc[i + 3][j + 2]);
                acc[i + 3][j + 2] = MFMA16(a1[i][1], b1[j][1], acc[i + 3][j + 2]);
            }
        __builtin_amdgcn_s_setprio(0);
        pbar();

        // ---- phase 4: Q(0,1) -- reuse a0, b1 (no reads) ----
        __builtin_amdgcn_s_setprio(1);
#pragma unroll
        for (int i = 0; i < 3; i++)
#pragma unroll
            for (int j = 0; j < 2; j++) {
                acc[i][j + 2] = MFMA16(a0[i][0], b1[j][0], acc[i][j + 2]);
                acc[i][j + 2] = MFMA16(a0[i][1], b1[j][1], acc[i][j + 2]);
            }
        __builtin_amdgcn_s_setprio(0);
        // step-boundary __syncthreads at loop top separates phase 4 from
        // the next step's staging overwrite of buf[set^1].
    }

    // ---- epilogue: bias + per-i scale; V third transposed into vT ----
#pragma unroll
    for (int i = 0; i < 6; i++) {
        const int f0i = fb + wm * 96 + i * 16;       // 16-aligned group base
        const int f0  = f0i + qd * 4;
        const float scale = (f0i < 1024) ? 0.125f * LOG2E : 1.0f;
        const bool vblk = (f0i >= 2048);
        float bs[4];
#pragma unroll
        for (int r = 0; r < 4; r++) bs[r] = bias[f0 + r];
#pragma unroll
        for (int j = 0; j < 4; j++) {
            const int m = mb + wn * 64 + j * 16 + l15;
            if (vblk) {
                const int sIdx = m >> 1;          // B = 2 row interleave
                const int b2   = (m & 1) << 4;    // b*16
#pragma unroll
                for (int r = 0; r < 4; r++) {
                    const int fv = f0 + r - 2048;
                    vtp[(size_t)((b2 + (fv >> 6)) * 64 + (fv & 63)) * 2048 + sIdx] =
                        (bf16_t)(acc[i][j][r] + bs[r]);
                }
            } else {
                bf16x4 o;
#pragma unroll
                for (int r = 0; r < 4; r++)
                    o[r] = (bf16_t)((acc[i][j][r] + bs[r]) * scale);
                *reinterpret_cast<bf16x4*>(qkv + (size_t)m * 3072 + f0) = o;
            }
        }
    }
}

// ---------------------------------------------------------------------------
// NT GEMM (out-proj), double-buffered BK=32, one barrier per K-iter. Tile
// 128(f) x MT(m). 1D grid with XCD swizzle. MT=64 -> 512 blocks (2/CU).
// ---------------------------------------------------------------------------
template <int MT, bool F32OUT>
__global__ __launch_bounds__(256, 3) void gemm_nt_lds(
    const bf16_t* __restrict__ W, const bf16_t* __restrict__ X,
    const float* __restrict__ bias, void* __restrict__ Cv,
    int N, int K, int fpx)
{
    constexpr int NJ = MT / 32;
    __shared__ bf16_t As[2][128 * 32];
    __shared__ bf16_t Bs[2][MT * 32];

    const int lane = threadIdx.x & 63;
    const int wv   = threadIdx.x >> 6;
    const int l15  = lane & 15;
    const int qd   = lane >> 4;

    const int id = blockIdx.x;
    const int x8 = id & 7, k = id >> 3;
    const int fb = ((k % fpx) * 8 + x8) * 128;
    const int mb = (k / fpx) * MT;
    const int fw = (wv & 1) * 64;
    const int mw = (wv >> 1) * (MT / 2);

    f32x4 acc[4][NJ] = {};

    auto stage = [&](int set, int k0) {
#pragma unroll
        for (int t = 0; t < 2; t++) {
            const int p = (wv * 2 + t) * 64 + lane;
            const int r = p >> 2, cl = (p & 3) ^ (r & 3);
            async16(W + (size_t)(fb + r) * K + k0 + cl * 8,
                    &As[set][(wv * 2 + t) * 512]);
        }
#pragma unroll
        for (int t = 0; t < MT / 64; t++) {
            const int p = (wv * (MT / 64) + t) * 64 + lane;
            const int r = p >> 2, cl = (p & 3) ^ (r & 3);
            async16(X + (size_t)(mb + r) * K + k0 + cl * 8,
                    &Bs[set][(wv * (MT / 64) + t) * 512]);
        }
    };

    stage(0, 0);
    int set = 0;
    for (int k0 = 0; k0 < K; k0 += 32) {
        __syncthreads();
        if (k0 + 32 < K) stage(set ^ 1, k0 + 32);

        const int s3 = l15 & 3;
        bf16x8 a[4], bb[NJ];
#pragma unroll
        for (int i = 0; i < 4; i++)
            a[i] = *reinterpret_cast<const bf16x8*>(
                &As[set][(fw + i * 16 + l15) * 32 + ((qd ^ s3) * 8)]);
#pragma unroll
        for (int j = 0; j < NJ; j++)
            bb[j] = *reinterpret_cast<const bf16x8*>(
                &Bs[set][(mw + j * 16 + l15) * 32 + ((qd ^ s3) * 8)]);
#pragma unroll
        for (int i = 0; i < 4; i++)
#pragma unroll
            for (int j = 0; j < NJ; j++)
                acc[i][j] = MFMA16(a[i], bb[j], acc[i][j]);
        set ^= 1;
    }

#pragma unroll
    for (int i = 0; i < 4; i++) {
        const int f0 = fb + fw + i * 16 + qd * 4;
        float bs[4];
#pragma unroll
        for (int r = 0; r < 4; r++) bs[r] = bias[f0 + r];
#pragma unroll
        for (int j = 0; j < NJ; j++) {
            const int m = mb + mw + j * 16 + l15;
            if (F32OUT) {
                float4 o;
                o.x = acc[i][j][0] + bs[0];
                o.y = acc[i][j][1] + bs[1];
                o.z = acc[i][j][2] + bs[2];
                o.w = acc[i][j][3] + bs[3];
                *reinterpret_cast<float4*>((float*)Cv + (size_t)m * N + f0) = o;
            } else {
                bf16x4 o;
#pragma unroll
                for (int r = 0; r < 4; r++)
                    o[r] = (bf16_t)(acc[i][j][r] + bs[r]);
                *reinterpret_cast<bf16x4*>((bf16_t*)Cv + (size_t)m * N + f0) = o;
            }
        }
    }
}

// ---------------------------------------------------------------------------
// Flash attention with IN-BLOCK KV-split x2 (exact R2 kernel, verified
// 54.0 us). Block = 4 waves / 128 q. Grid 32 bh x 16 = 512 blocks, 2/CU.
// ---------------------------------------------------------------------------
__global__ __launch_bounds__(256, 2) void flash_attn(
    const bf16_t* __restrict__ qkv, const bf16_t* __restrict__ vT,
    bf16_t* __restrict__ attn, int S, int B)
{
    const int E3 = 3072, E = 1024;
    const int bh = blockIdx.x, b = bh >> 4, h = bh & 15;
    const int tid = threadIdx.x, lane = tid & 63, wv = tid >> 6;  // 0..3
    const int qw = wv & 1;               // q sub-block (64 q each)
    const int pr = wv >> 1;              // KV half
    const int l31 = lane & 31, half = lane >> 5;

    __shared__ bf16_t Kt[2][2][64 * 64];  // [pair][set]; chunk c at c^(r&7)
    __shared__ bf16_t Vt[2][2][64 * 64];  // [pair][set]; row d, chunk c at c^(d&7)
    __shared__ float  lsh[2][64];

    const int q0 = blockIdx.y * 128 + qw * 64;

    bf16x8 qf[2][4];                     // Q[q][k = ks*16 + half*8 + j]
#pragma unroll
    for (int qt = 0; qt < 2; qt++) {
        const bf16_t* qp = qkv + (size_t)((q0 + qt * 32 + l31) * B + b) * E3 + h * 64;
#pragma unroll
        for (int ks = 0; ks < 4; ks++)
            qf[qt][ks] = *reinterpret_cast<const bf16x8*>(qp + ks * 16 + half * 8);
    }

    f32x16 oacc[2][2] = {};              // [qt][d-tile]; row=d col=q
    float lrun[2] = {0.0f, 0.0f};

    auto stage = [&](int set, int kv) {
#pragma unroll
        for (int t = 0; t < 4; t++) {
            const int p = (qw * 4 + t) * 64 + lane;     // phys chunk 0..511
            const int r = p >> 3, cl = (p & 7) ^ (r & 7);
            async16(qkv + (size_t)((kv + r) * B + b) * E3 + E + h * 64 + cl * 8,
                    &Kt[pr][set][(qw * 4 + t) * 512]);
            async16(vT + (size_t)(bh * 64 + r) * 2048 + kv + cl * 8,
                    &Vt[pr][set][(qw * 4 + t) * 512]);
        }
    };

    const int kvbase = pr * (S / 2);
    const int NIT = S / 128;             // 16 iters of 64 per pair

    stage(0, kvbase);
    int set = 0;
    for (int it = 0; it < NIT; it++) {
        __syncthreads();                 // buf[set] ready; buf[set^1] free
        if (it + 1 < NIT) stage(set ^ 1, kvbase + (it + 1) * 64);

        const bf16_t* K_ = Kt[pr][set];
        const bf16_t* V_ = Vt[pr][set];

        union PF { unsigned u[4]; bf16x8 v; };
        PF pf[2][4];
#pragma unroll
        for (int nt = 0; nt < 2; nt++) {
            const int r = nt * 32 + l31;
            const int r7 = r & 7;
            bf16x8 kf[4];
#pragma unroll
            for (int ks = 0; ks < 4; ks++)
                kf[ks] = *reinterpret_cast<const bf16x8*>(
                    K_ + r * 64 + (((ks * 2 + half) ^ r7) * 8));
#pragma unroll
            for (int qt = 0; qt < 2; qt++) {
                f32x16 st = {};
                __builtin_amdgcn_s_setprio(1);
#pragma unroll
                for (int ks = 0; ks < 4; ks++)
                    st = MFMA32(kf[ks], qf[qt][ks], st);
                __builtin_amdgcn_s_setprio(0);
                float ls = 0.0f;
                unsigned q8[8];
#pragma unroll
                for (int g = 0; g < 4; g++) {
                    const float p0 = __builtin_amdgcn_exp2f(st[4 * g]);
                    const float p1 = __builtin_amdgcn_exp2f(st[4 * g + 1]);
                    const float p2 = __builtin_amdgcn_exp2f(st[4 * g + 2]);
                    const float p3 = __builtin_amdgcn_exp2f(st[4 * g + 3]);
                    ls += (p0 + p1) + (p2 + p3);
                    q8[2 * g]     = pack2(p0, p1);
                    q8[2 * g + 1] = pack2(p2, p3);
                }
                lrun[qt] += ls;
                pl32swap(q8[0], q8[2]); pl32swap(q8[1], q8[3]);
                pl32swap(q8[4], q8[6]); pl32swap(q8[5], q8[7]);
                pf[qt][nt * 2 + 0].u[0] = q8[0]; pf[qt][nt * 2 + 0].u[1] = q8[1];
                pf[qt][nt * 2 + 0].u[2] = q8[2]; pf[qt][nt * 2 + 0].u[3] = q8[3];
                pf[qt][nt * 2 + 1].u[0] = q8[4]; pf[qt][nt * 2 + 1].u[1] = q8[5];
                pf[qt][nt * 2 + 1].u[2] = q8[6]; pf[qt][nt * 2 + 1].u[3] = q8[7];
            }
        }
        __builtin_amdgcn_s_setprio(1);
#pragma unroll
        for (int kn = 0; kn < 4; kn++)
#pragma unroll
            for (int dt = 0; dt < 2; dt++) {
                const int d = dt * 32 + l31;
                bf16x8 vf = *reinterpret_cast<const bf16x8*>(
                    V_ + d * 64 + (((kn * 2 + half) ^ (d & 7)) * 8));
                oacc[0][dt] = MFMA32(vf, pf[0][kn].v, oacc[0][dt]);
                oacc[1][dt] = MFMA32(vf, pf[1][kn].v, oacc[1][dt]);
            }
        __builtin_amdgcn_s_setprio(0);
        set ^= 1;
    }

    // --- Epilogue: merge the two KV halves through LDS, normalize, store ---
    __syncthreads();                     // all K/V reads done; LDS reusable
    float lr[2];
#pragma unroll
    for (int qt = 0; qt < 2; qt++) lr[qt] = lrun[qt] + __shfl_xor(lrun[qt], 32);

    // fp32 scratch overlays Kt (32 KB = 2 regions x 64q x 64d), d-major
    float* fo = reinterpret_cast<float*>(&Kt[0][0][0]) + qw * 4096;

    if (pr == 1) {
#pragma unroll
        for (int qt = 0; qt < 2; qt++) {
            const int ql = qt * 32 + l31;
            lsh[qw][ql] = lr[qt];        // both halves write same value
#pragma unroll
            for (int dt = 0; dt < 2; dt++)
#pragma unroll
                for (int g = 0; g < 4; g++)
#pragma unroll
                    for (int r = 0; r < 4; r++) {
                        const int d = dt * 32 + g * 8 + half * 4 + r;
                        fo[d * 64 + ql] = oacc[qt][dt][4 * g + r];
                    }
        }
    }
    __syncthreads();
    if (pr == 0) {
#pragma unroll
        for (int qt = 0; qt < 2; qt++) {
            const int ql = qt * 32 + l31;
            const float inv = 1.0f / (lr[qt] + lsh[qw][ql]);
            const int qrow = q0 + qt * 32 + l31;
#pragma unroll
            for (int dt = 0; dt < 2; dt++)
#pragma unroll
                for (int g = 0; g < 4; g++) {
                    bf16x4 o;
#pragma unroll
                    for (int r = 0; r < 4; r++) {
                        const int d = dt * 32 + g * 8 + half * 4 + r;
                        o[r] = (bf16_t)((oacc[qt][dt][4 * g + r] + fo[d * 64 + ql]) * inv);
                    }
                    *reinterpret_cast<bf16x4*>(attn + (size_t)(qrow * B + b) * E +
                                               h * 64 + dt * 32 + g * 8 + half * 4) = o;
                }
        }
    }
}

extern "C" void kernel_launch(void* const* d_in, const int* in_sizes, int n_in,
                              void* d_out, int out_size, void* d_ws, size_t ws_size,
                              hipStream_t stream) {
    const float* x  = (const float*)d_in[0];
    const float* wi = (const float*)d_in[1];
    const float* bi = (const float*)d_in[2];
    const float* wo = (const float*)d_in[3];
    const float* bo = (const float*)d_in[4];
    float* out = (float*)d_out;

    const int S = 2048, B = 2, E = 1024;
    const int M = S * B;

    // Workspace layout:
    //   xb [M,1024] bf16  -- X in bf16; dead after QKV GEMM
    //   wib[3072,1024]    -- W_in bf16
    //   wob[1024,1024]    -- W_out bf16
    //   qkv[M,3072]       -- Q,K written by GEMM; V third left unwritten
    //   vT [32][64][2048] -- V transposed, written by the GEMM epilogue
    //   attn = xb overlay -- flash output (xb dead by then)
    bf16_t* xb   = (bf16_t*)d_ws;
    bf16_t* wib  = xb  + (size_t)M * E;
    bf16_t* wob  = wib + (size_t)3 * E * E;
    bf16_t* qkv  = wob + (size_t)E * E;
    bf16_t* vT   = qkv + (size_t)M * 3 * E;
    bf16_t* attn = xb;

    // 0) fused fp32 -> bf16
    const int n0 = M * E, n1 = 3 * E * E, n2 = E * E;
    conv3<<<(n0 + n1 + n2) / 8 / 256, 256, 0, stream>>>(x, wi, wo, xb, n0, n1);

    // 1) QKV projection: 192x256 4-phase template, 256 blocks = 1/CU (full
    //    subscription); V third transposed into vT; qscale folded into q.
    gemm_qkv<<<256, 512, 0, stream>>>(wib, xb, bi, qkv, vT);

    // 2) Flash attention (exact R2 kernel; attn overlays dead xb)
    flash_attn<<<dim3(B * 16, S / 128), 256, 0, stream>>>(qkv, vT, attn, S, B);

    // 3) Output projection, MT=64 (512 blocks = 2/CU)
    gemm_nt_lds<64, true><<<(E / 128) * (M / 64), 256, 0, stream>>>(
        wob, attn, bo, out, E, E, 1);
}

// Round 9
// 182.156 us; speedup vs baseline: 1.0433x; 1.0079x over previous
//
#include <hip/hip_runtime.h>

typedef __bf16 bf16_t;
typedef __attribute__((ext_vector_type(8))) __bf16 bf16x8;
typedef __attribute__((ext_vector_type(4))) __bf16 bf16x4;
typedef __attribute__((ext_vector_type(4))) float f32x4;
typedef __attribute__((ext_vector_type(16))) float f32x16;
typedef __attribute__((ext_vector_type(2))) unsigned uint2v;

#define MFMA16(a, b, c) __builtin_amdgcn_mfma_f32_16x16x32_bf16((a), (b), (c), 0, 0, 0)
#define MFMA32(a, b, c) __builtin_amdgcn_mfma_f32_32x32x16_bf16((a), (b), (c), 0, 0, 0)
#define LOG2E 1.44269504088896f

// Async global->LDS 16B copy. LDS dest is the WAVE-UNIFORM base; HW places
// lane i's 16B at base + 16*i. gptr is per-lane.
__device__ __forceinline__ void async16(const bf16_t* g, bf16_t* l) {
    __builtin_amdgcn_global_load_lds(
        (const __attribute__((address_space(1))) unsigned int*)g,
        (__attribute__((address_space(3))) unsigned int*)l, 16, 0, 0);
}

__device__ __forceinline__ unsigned pack2(float a, float b) {
    union { bf16_t e[2]; unsigned u; } x;
    x.e[0] = (bf16_t)a; x.e[1] = (bf16_t)b;
    return x.u;
}

// lane[i]<->lane[i+32] half exchange on the VALU pipe (v_permlane32_swap_b32).
__device__ __forceinline__ void pl32swap(unsigned& a, unsigned& b) {
    uint2v r = __builtin_amdgcn_permlane32_swap(a, b, false, false);
    a = r[0]; b = r[1];
}

// Raw workgroup barrier WITHOUT the vmcnt(0) drain of __syncthreads.
__device__ __forceinline__ void pbar() {
    asm volatile("" ::: "memory");
    __builtin_amdgcn_s_barrier();
    asm volatile("" ::: "memory");
}

// ---------------------------------------------------------------------------
// Fused fp32 -> bf16 conversion of x / W_in / W_out into contiguous ws region.
// ---------------------------------------------------------------------------
__global__ __launch_bounds__(256) void conv3(
    const float* __restrict__ s0, const float* __restrict__ s1,
    const float* __restrict__ s2, bf16_t* __restrict__ dst,
    int n0, int n1)
{
    const int i = (blockIdx.x * 256 + threadIdx.x) * 8;
    const float* src;
    int off;
    if (i < n0)           { src = s0; off = 0; }
    else if (i < n0 + n1) { src = s1; off = n0; }
    else                  { src = s2; off = n0 + n1; }
    const float4 a = *reinterpret_cast<const float4*>(src + i - off);
    const float4 b = *reinterpret_cast<const float4*>(src + i - off + 4);
    bf16x8 o;
    o[0] = (bf16_t)a.x; o[1] = (bf16_t)a.y; o[2] = (bf16_t)a.z; o[3] = (bf16_t)a.w;
    o[4] = (bf16_t)b.x; o[5] = (bf16_t)b.y; o[6] = (bf16_t)b.z; o[7] = (bf16_t)b.w;
    *reinterpret_cast<bf16x8*>(dst + i) = o;
}

// ---------------------------------------------------------------------------
// QKV projection GEMM -- 192(f) x 256(m) tile, BK=64, 8 waves, 4-phase
// quadrant schedule, 256 blocks = 1/CU (R8-verified: -5 us vs 2-phase).
// ---------------------------------------------------------------------------
__global__ __launch_bounds__(512, 2) void gemm_qkv(
    const bf16_t* __restrict__ W, const bf16_t* __restrict__ X,
    const float* __restrict__ bias, bf16_t* __restrict__ qkv,
    bf16_t* __restrict__ vtp)
{
    constexpr int K = 1024;
    constexpr int NSTEP = K / 64;        // 16
    constexpr int AELEM = 192 * 64;      // 12288 elems = 24 KB
    constexpr int BELEM = 256 * 64;      // 16384 elems = 32 KB

    __shared__ bf16_t lds[2][AELEM + BELEM];   // 112 KB total

    const int tid  = threadIdx.x;        // 0..511
    const int lane = tid & 63;
    const int wv   = tid >> 6;           // 0..7
    const int wm   = wv >> 2;            // f-half of 192 (96 rows each)
    const int wn   = wv & 3;             // m-quarter of 256 (64 rows each)
    const int l15  = lane & 15;
    const int qd   = lane >> 4;

    const int id = blockIdx.x;           // 0..255
    const int x8 = id & 7, k = id >> 3;  // k 0..31
    const int mb = ((k & 1) * 8 + x8) * 256;
    const int fb = (k >> 1) * 192;

    f32x4 acc[6][4] = {};                // [i: f frag 0..5][j: m frag 0..3]

    auto stage = [&](int set, int k0) {
        bf16_t* Ab = lds[set];
        bf16_t* Bb = lds[set] + AELEM;
#pragma unroll
        for (int t = 0; t < 3; t++) {    // A: 192 rows = 1536 chunks
            const int p = t * 512 + tid;
            const int r = p >> 3;
            const int c = (p & 7) ^ (r & 7);
            async16(W + (size_t)(fb + r) * K + k0 + c * 8,
                    Ab + (t * 512 + wv * 64) * 8);
        }
#pragma unroll
        for (int t = 0; t < 4; t++) {    // B: 256 rows = 2048 chunks
            const int p = t * 512 + tid;
            const int r = p >> 3;
            const int c = (p & 7) ^ (r & 7);
            async16(X + (size_t)(mb + r) * K + k0 + c * 8,
                    Bb + (t * 512 + wv * 64) * 8);
        }
    };

    stage(0, 0);                         // prologue: step 0 -> buf 0
    for (int s = 0; s < NSTEP; s++) {
        const int set = s & 1;
        __syncthreads();                 // buf[set] staging drained; fence
        if (s + 1 < NSTEP) stage(set ^ 1, (s + 1) * 64);

        const bf16_t* Ab = lds[set];
        const bf16_t* Bb = lds[set] + AELEM;

        bf16x8 a0[3][2], a1[3][2], b0[2][2], b1[2][2];

        // ---- phase 1: Q(0,0) -- load a0 (i=0..2), b0 (j=0..1) ----
#pragma unroll
        for (int i = 0; i < 3; i++) {
            const int r = wm * 96 + i * 16 + l15;
            a0[i][0] = *reinterpret_cast<const bf16x8*>(
                Ab + r * 64 + ((qd ^ (r & 7)) * 8));
            a0[i][1] = *reinterpret_cast<const bf16x8*>(
                Ab + r * 64 + (((4 + qd) ^ (r & 7)) * 8));
        }
#pragma unroll
        for (int j = 0; j < 2; j++) {
            const int r = wn * 64 + j * 16 + l15;
            b0[j][0] = *reinterpret_cast<const bf16x8*>(
                Bb + r * 64 + ((qd ^ (r & 7)) * 8));
            b0[j][1] = *reinterpret_cast<const bf16x8*>(
                Bb + r * 64 + (((4 + qd) ^ (r & 7)) * 8));
        }
        __builtin_amdgcn_s_setprio(1);
#pragma unroll
        for (int i = 0; i < 3; i++)
#pragma unroll
            for (int j = 0; j < 2; j++) {
                acc[i][j] = MFMA16(a0[i][0], b0[j][0], acc[i][j]);
                acc[i][j] = MFMA16(a0[i][1], b0[j][1], acc[i][j]);
            }
        __builtin_amdgcn_s_setprio(0);
        pbar();

        // ---- phase 2: Q(1,0) -- load a1 (i=3..5), reuse b0 ----
#pragma unroll
        for (int i = 0; i < 3; i++) {
            const int r = wm * 96 + (i + 3) * 16 + l15;
            a1[i][0] = *reinterpret_cast<const bf16x8*>(
                Ab + r * 64 + ((qd ^ (r & 7)) * 8));
            a1[i][1] = *reinterpret_cast<const bf16x8*>(
                Ab + r * 64 + (((4 + qd) ^ (r & 7)) * 8));
        }
        __builtin_amdgcn_s_setprio(1);
#pragma unroll
        for (int i = 0; i < 3; i++)
#pragma unroll
            for (int j = 0; j < 2; j++) {
                acc[i + 3][j] = MFMA16(a1[i][0], b0[j][0], acc[i + 3][j]);
                acc[i + 3][j] = MFMA16(a1[i][1], b0[j][1], acc[i + 3][j]);
            }
        __builtin_amdgcn_s_setprio(0);
        pbar();

        // ---- phase 3: Q(1,1) -- load b1 (j=2..3), reuse a1 ----
#pragma unroll
        for (int j = 0; j < 2; j++) {
            const int r = wn * 64 + (j + 2) * 16 + l15;
            b1[j][0] = *reinterpret_cast<const bf16x8*>(
                Bb + r * 64 + ((qd ^ (r & 7)) * 8));
            b1[j][1] = *reinterpret_cast<const bf16x8*>(
                Bb + r * 64 + (((4 + qd) ^ (r & 7)) * 8));
        }
        __builtin_amdgcn_s_setprio(1);
#pragma unroll
        for (int i = 0; i < 3; i++)
#pragma unroll
            for (int j = 0; j < 2; j++) {
                acc[i + 3][j + 2] = MFMA16(a1[i][0], b1[j][0], acc[i + 3][j + 2]);
                acc[i + 3][j + 2] = MFMA16(a1[i][1], b1[j][1], acc[i + 3][j + 2]);
            }
        __builtin_amdgcn_s_setprio(0);
        pbar();

        // ---- phase 4: Q(0,1) -- reuse a0, b1 (no reads) ----
        __builtin_amdgcn_s_setprio(1);
#pragma unroll
        for (int i = 0; i < 3; i++)
#pragma unroll
            for (int j = 0; j < 2; j++) {
                acc[i][j + 2] = MFMA16(a0[i][0], b1[j][0], acc[i][j + 2]);
                acc[i][j + 2] = MFMA16(a0[i][1], b1[j][1], acc[i][j + 2]);
            }
        __builtin_amdgcn_s_setprio(0);
    }

    // ---- epilogue: bias + per-i scale; V third transposed into vT ----
#pragma unroll
    for (int i = 0; i < 6; i++) {
        const int f0i = fb + wm * 96 + i * 16;       // 16-aligned group base
        const int f0  = f0i + qd * 4;
        const float scale = (f0i < 1024) ? 0.125f * LOG2E : 1.0f;
        const bool vblk = (f0i >= 2048);
        float bs[4];
#pragma unroll
        for (int r = 0; r < 4; r++) bs[r] = bias[f0 + r];
#pragma unroll
        for (int j = 0; j < 4; j++) {
            const int m = mb + wn * 64 + j * 16 + l15;
            if (vblk) {
                const int sIdx = m >> 1;          // B = 2 row interleave
                const int b2   = (m & 1) << 4;    // b*16
#pragma unroll
                for (int r = 0; r < 4; r++) {
                    const int fv = f0 + r - 2048;
                    vtp[(size_t)((b2 + (fv >> 6)) * 64 + (fv & 63)) * 2048 + sIdx] =
                        (bf16_t)(acc[i][j][r] + bs[r]);
                }
            } else {
                bf16x4 o;
#pragma unroll
                for (int r = 0; r < 4; r++)
                    o[r] = (bf16_t)((acc[i][j][r] + bs[r]) * scale);
                *reinterpret_cast<bf16x4*>(qkv + (size_t)m * 3072 + f0) = o;
            }
        }
    }
}

// ---------------------------------------------------------------------------
// NT GEMM (out-proj), double-buffered BK=32, one barrier per K-iter. Tile
// 128(f) x MT(m). 1D grid with XCD swizzle. MT=64 -> 512 blocks (2/CU).
// ---------------------------------------------------------------------------
template <int MT, bool F32OUT>
__global__ __launch_bounds__(256, 3) void gemm_nt_lds(
    const bf16_t* __restrict__ W, const bf16_t* __restrict__ X,
    const float* __restrict__ bias, void* __restrict__ Cv,
    int N, int K, int fpx)
{
    constexpr int NJ = MT / 32;
    __shared__ bf16_t As[2][128 * 32];
    __shared__ bf16_t Bs[2][MT * 32];

    const int lane = threadIdx.x & 63;
    const int wv   = threadIdx.x >> 6;
    const int l15  = lane & 15;
    const int qd   = lane >> 4;

    const int id = blockIdx.x;
    const int x8 = id & 7, k = id >> 3;
    const int fb = ((k % fpx) * 8 + x8) * 128;
    const int mb = (k / fpx) * MT;
    const int fw = (wv & 1) * 64;
    const int mw = (wv >> 1) * (MT / 2);

    f32x4 acc[4][NJ] = {};

    auto stage = [&](int set, int k0) {
#pragma unroll
        for (int t = 0; t < 2; t++) {
            const int p = (wv * 2 + t) * 64 + lane;
            const int r = p >> 2, cl = (p & 3) ^ (r & 3);
            async16(W + (size_t)(fb + r) * K + k0 + cl * 8,
                    &As[set][(wv * 2 + t) * 512]);
        }
#pragma unroll
        for (int t = 0; t < MT / 64; t++) {
            const int p = (wv * (MT / 64) + t) * 64 + lane;
            const int r = p >> 2, cl = (p & 3) ^ (r & 3);
            async16(X + (size_t)(mb + r) * K + k0 + cl * 8,
                    &Bs[set][(wv * (MT / 64) + t) * 512]);
        }
    };

    stage(0, 0);
    int set = 0;
    for (int k0 = 0; k0 < K; k0 += 32) {
        __syncthreads();
        if (k0 + 32 < K) stage(set ^ 1, k0 + 32);

        const int s3 = l15 & 3;
        bf16x8 a[4], bb[NJ];
#pragma unroll
        for (int i = 0; i < 4; i++)
            a[i] = *reinterpret_cast<const bf16x8*>(
                &As[set][(fw + i * 16 + l15) * 32 + ((qd ^ s3) * 8)]);
#pragma unroll
        for (int j = 0; j < NJ; j++)
            bb[j] = *reinterpret_cast<const bf16x8*>(
                &Bs[set][(mw + j * 16 + l15) * 32 + ((qd ^ s3) * 8)]);
#pragma unroll
        for (int i = 0; i < 4; i++)
#pragma unroll
            for (int j = 0; j < NJ; j++)
                acc[i][j] = MFMA16(a[i], bb[j], acc[i][j]);
        set ^= 1;
    }

#pragma unroll
    for (int i = 0; i < 4; i++) {
        const int f0 = fb + fw + i * 16 + qd * 4;
        float bs[4];
#pragma unroll
        for (int r = 0; r < 4; r++) bs[r] = bias[f0 + r];
#pragma unroll
        for (int j = 0; j < NJ; j++) {
            const int m = mb + mw + j * 16 + l15;
            if (F32OUT) {
                float4 o;
                o.x = acc[i][j][0] + bs[0];
                o.y = acc[i][j][1] + bs[1];
                o.z = acc[i][j][2] + bs[2];
                o.w = acc[i][j][3] + bs[3];
                *reinterpret_cast<float4*>((float*)Cv + (size_t)m * N + f0) = o;
            } else {
                bf16x4 o;
#pragma unroll
                for (int r = 0; r < 4; r++)
                    o[r] = (bf16_t)(acc[i][j][r] + bs[r]);
                *reinterpret_cast<bf16x4*>((bf16_t*)Cv + (size_t)m * N + f0) = o;
            }
        }
    }
}

// ---------------------------------------------------------------------------
// Flash attention, IN-BLOCK KV-split x2 + P-LAG PIPELINE (macro-expanded,
// fully static -- R4's lambda-by-reference scratch trap eliminated).
// Block = 4 waves / 128 q: wave = {pr = wv>>1 (KV half), qw = wv&1 (64-q
// sub-block)}. Grid 32 bh x 16 = 512 blocks (2/CU, grid-capped).
// P-lag: PV(it-1) -- 16 independent MFMAs -- is interleaved into iter it's
// QK-latency window (after the 4 QK MFMAs issue, before softmax reads st).
// pf double-buffered as two NAMED arrays pfA/pfB; the loop processes even/
// odd iteration pairs so write/read roles are compile-time (rule #20 safe).
// V staged one iter early: V(it) -> vset it&1 issued at iter it, read at
// it+1 after the loop-top barrier (write-set and read-set never collide;
// scheme numerically verified in R4). kn->dt->qt accumulation order kept ->
// bit-identical output. Final PV drains behind the epilogue barrier.
// ---------------------------------------------------------------------------
#define FLASH_ITER(IT, PW, PR)                                               \
  {                                                                          \
    __syncthreads();                                                         \
    if ((IT) + 1 < NIT) stageK(set ^ 1, kvbase + ((IT) + 1) * 64);           \
    if ((IT) > 0)       stageV((IT) & 1, kvbase + (IT) * 64);                \
    const bf16_t* K_ = Kt[pr][set];                                          \
    const bf16_t* Vp = Vt[pr][((IT) & 1) ^ 1];                               \
    const bool doPV = (IT) > 0;                                              \
    _Pragma("unroll")                                                        \
    for (int nt = 0; nt < 2; nt++) {                                         \
      const int r = nt * 32 + l31;                                           \
      const int r7 = r & 7;                                                  \
      bf16x8 kf[4];                                                          \
      _Pragma("unroll")                                                      \
      for (int ks = 0; ks < 4; ks++)                                         \
        kf[ks] = *reinterpret_cast<const bf16x8*>(                           \
            K_ + r * 64 + (((ks * 2 + half) ^ r7) * 8));                     \
      _Pragma("unroll")                                                      \
      for (int qt = 0; qt < 2; qt++) {                                       \
        f32x16 st = {};                                                      \
        __builtin_amdgcn_s_setprio(1);                                       \
        _Pragma("unroll")                                                    \
        for (int ks = 0; ks < 4; ks++)                                       \
          st = MFMA32(kf[ks], qf[qt][ks], st);                               \
        if (doPV) {                                                          \
          const int kn = nt * 2 + qt;                                        \
          _Pragma("unroll")                                                  \
          for (int dt = 0; dt < 2; dt++) {                                   \
            const int d = dt * 32 + l31;                                     \
            bf16x8 vf = *reinterpret_cast<const bf16x8*>(                    \
                Vp + d * 64 + (((kn * 2 + half) ^ (d & 7)) * 8));            \
            oacc[0][dt] = MFMA32(vf, PR[0][kn].v, oacc[0][dt]);              \
            oacc[1][dt] = MFMA32(vf, PR[1][kn].v, oacc[1][dt]);              \
          }                                                                  \
        }                                                                    \
        __builtin_amdgcn_s_setprio(0);                                       \
        float ls = 0.0f;                                                     \
        unsigned q8[8];                                                      \
        _Pragma("unroll")                                                    \
        for (int g = 0; g < 4; g++) {                                        \
          const float p0 = __builtin_amdgcn_exp2f(st[4 * g]);                \
          const float p1 = __builtin_amdgcn_exp2f(st[4 * g + 1]);            \
          const float p2 = __builtin_amdgcn_exp2f(st[4 * g + 2]);            \
          const float p3 = __builtin_amdgcn_exp2f(st[4 * g + 3]);            \
          ls += (p0 + p1) + (p2 + p3);                                       \
          q8[2 * g]     = pack2(p0, p1);                                     \
          q8[2 * g + 1] = pack2(p2, p3);                                     \
        }                                                                    \
        lrun[qt] += ls;                                                      \
        pl32swap(q8[0], q8[2]); pl32swap(q8[1], q8[3]);                      \
        pl32swap(q8[4], q8[6]); pl32swap(q8[5], q8[7]);                      \
        PW[qt][nt * 2 + 0].u[0] = q8[0]; PW[qt][nt * 2 + 0].u[1] = q8[1];    \
        PW[qt][nt * 2 + 0].u[2] = q8[2]; PW[qt][nt * 2 + 0].u[3] = q8[3];    \
        PW[qt][nt * 2 + 1].u[0] = q8[4]; PW[qt][nt * 2 + 1].u[1] = q8[5];    \
        PW[qt][nt * 2 + 1].u[2] = q8[6]; PW[qt][nt * 2 + 1].u[3] = q8[7];    \
      }                                                                      \
    }                                                                        \
    set ^= 1;                                                                \
  }

__global__ __launch_bounds__(256, 2) void flash_attn(
    const bf16_t* __restrict__ qkv, const bf16_t* __restrict__ vT,
    bf16_t* __restrict__ attn, int S, int B)
{
    const int E3 = 3072, E = 1024;
    const int bh = blockIdx.x, b = bh >> 4, h = bh & 15;
    const int tid = threadIdx.x, lane = tid & 63, wv = tid >> 6;  // 0..3
    const int qw = wv & 1;               // q sub-block (64 q each)
    const int pr = wv >> 1;              // KV half
    const int l31 = lane & 31, half = lane >> 5;

    __shared__ bf16_t Kt[2][2][64 * 64];  // [pair][set]; chunk c at c^(r&7)
    __shared__ bf16_t Vt[2][2][64 * 64];  // [pair][set]; row d, chunk c at c^(d&7)
    __shared__ float  lsh[2][64];

    const int q0 = blockIdx.y * 128 + qw * 64;

    bf16x8 qf[2][4];                     // Q[q][k = ks*16 + half*8 + j]
#pragma unroll
    for (int qt = 0; qt < 2; qt++) {
        const bf16_t* qp = qkv + (size_t)((q0 + qt * 32 + l31) * B + b) * E3 + h * 64;
#pragma unroll
        for (int ks = 0; ks < 4; ks++)
            qf[qt][ks] = *reinterpret_cast<const bf16x8*>(qp + ks * 16 + half * 8);
    }

    f32x16 oacc[2][2] = {};              // [qt][d-tile]; row=d col=q
    float lrun[2] = {0.0f, 0.0f};

    auto stageK = [&](int set_, int kv) {
#pragma unroll
        for (int t = 0; t < 4; t++) {
            const int p = (qw * 4 + t) * 64 + lane;     // phys chunk 0..511
            const int r = p >> 3, cl = (p & 7) ^ (r & 7);
            async16(qkv + (size_t)((kv + r) * B + b) * E3 + E + h * 64 + cl * 8,
                    &Kt[pr][set_][(qw * 4 + t) * 512]);
        }
    };
    auto stageV = [&](int vset, int kv) {
#pragma unroll
        for (int t = 0; t < 4; t++) {
            const int p = (qw * 4 + t) * 64 + lane;
            const int r = p >> 3, cl = (p & 7) ^ (r & 7);
            async16(vT + (size_t)(bh * 64 + r) * 2048 + kv + cl * 8,
                    &Vt[pr][vset][(qw * 4 + t) * 512]);
        }
    };

    union PF { unsigned u[4]; bf16x8 v; };
    PF pfA[2][4], pfB[2][4];

    const int kvbase = pr * (S / 2);
    const int NIT = S / 128;             // 16 iters of 64 per pair (even)

    stageK(0, kvbase);
    stageV(0, kvbase);                   // V(0) -> vset 0
    int set = 0;
    for (int it = 0; it < NIT; it += 2) {
        FLASH_ITER(it,     pfA, pfB)     // even: writes pfA, PV from pfB
        FLASH_ITER(it + 1, pfB, pfA)     // odd:  writes pfB, PV from pfA
    }

    // --- Epilogue: final PV drain, merge KV halves, normalize, store ---
    __syncthreads();                     // V(NIT-1) staged-writes visible
    {
        const bf16_t* Vp = Vt[pr][(NIT - 1) & 1];   // = vset 1 (NIT even)
        __builtin_amdgcn_s_setprio(1);
#pragma unroll
        for (int kn = 0; kn < 4; kn++)
#pragma unroll
            for (int dt = 0; dt < 2; dt++) {
                const int d = dt * 32 + l31;
                bf16x8 vf = *reinterpret_cast<const bf16x8*>(
                    Vp + d * 64 + (((kn * 2 + half) ^ (d & 7)) * 8));
                oacc[0][dt] = MFMA32(vf, pfB[0][kn].v, oacc[0][dt]);
                oacc[1][dt] = MFMA32(vf, pfB[1][kn].v, oacc[1][dt]);
            }
        __builtin_amdgcn_s_setprio(0);
    }

    float lr[2];
#pragma unroll
    for (int qt = 0; qt < 2; qt++) lr[qt] = lrun[qt] + __shfl_xor(lrun[qt], 32);

    // fp32 scratch overlays Kt (32 KB = 2 regions x 64q x 64d), d-major
    float* fo = reinterpret_cast<float*>(&Kt[0][0][0]) + qw * 4096;

    if (pr == 1) {
#pragma unroll
        for (int qt = 0; qt < 2; qt++) {
            const int ql = qt * 32 + l31;
            lsh[qw][ql] = lr[qt];        // both halves write same value
#pragma unroll
            for (int dt = 0; dt < 2; dt++)
#pragma unroll
                for (int g = 0; g < 4; g++)
#pragma unroll
                    for (int r = 0; r < 4; r++) {
                        const int d = dt * 32 + g * 8 + half * 4 + r;
                        fo[d * 64 + ql] = oacc[qt][dt][4 * g + r];
                    }
        }
    }
    __syncthreads();
    if (pr == 0) {
#pragma unroll
        for (int qt = 0; qt < 2; qt++) {
            const int ql = qt * 32 + l31;
            const float inv = 1.0f / (lr[qt] + lsh[qw][ql]);
            const int qrow = q0 + qt * 32 + l31;
#pragma unroll
            for (int dt = 0; dt < 2; dt++)
#pragma unroll
                for (int g = 0; g < 4; g++) {
                    bf16x4 o;
#pragma unroll
                    for (int r = 0; r < 4; r++) {
                        const int d = dt * 32 + g * 8 + half * 4 + r;
                        o[r] = (bf16_t)((oacc[qt][dt][4 * g + r] + fo[d * 64 + ql]) * inv);
                    }
                    *reinterpret_cast<bf16x4*>(attn + (size_t)(qrow * B + b) * E +
                                               h * 64 + dt * 32 + g * 8 + half * 4) = o;
                }
        }
    }
}

extern "C" void kernel_launch(void* const* d_in, const int* in_sizes, int n_in,
                              void* d_out, int out_size, void* d_ws, size_t ws_size,
                              hipStream_t stream) {
    const float* x  = (const float*)d_in[0];
    const float* wi = (const float*)d_in[1];
    const float* bi = (const float*)d_in[2];
    const float* wo = (const float*)d_in[3];
    const float* bo = (const float*)d_in[4];
    float* out = (float*)d_out;

    const int S = 2048, B = 2, E = 1024;
    const int M = S * B;

    // Workspace layout:
    //   xb [M,1024] bf16  -- X in bf16; dead after QKV GEMM
    //   wib[3072,1024]    -- W_in bf16
    //   wob[1024,1024]    -- W_out bf16
    //   qkv[M,3072]       -- Q,K written by GEMM; V third left unwritten
    //   vT [32][64][2048] -- V transposed, written by the GEMM epilogue
    //   attn = xb overlay -- flash output (xb dead by then)
    bf16_t* xb   = (bf16_t*)d_ws;
    bf16_t* wib  = xb  + (size_t)M * E;
    bf16_t* wob  = wib + (size_t)3 * E * E;
    bf16_t* qkv  = wob + (size_t)E * E;
    bf16_t* vT   = qkv + (size_t)M * 3 * E;
    bf16_t* attn = xb;

    // 0) fused fp32 -> bf16
    const int n0 = M * E, n1 = 3 * E * E, n2 = E * E;
    conv3<<<(n0 + n1 + n2) / 8 / 256, 256, 0, stream>>>(x, wi, wo, xb, n0, n1);

    // 1) QKV projection: 192x256 4-phase template, 256 blocks = 1/CU;
    //    V third transposed into vT; qscale folded into q.
    gemm_qkv<<<256, 512, 0, stream>>>(wib, xb, bi, qkv, vT);

    // 2) Flash attention (P-lag pipeline; attn overlays dead xb)
    flash_attn<<<dim3(B * 16, S / 128), 256, 0, stream>>>(qkv, vT, attn, S, B);

    // 3) Output projection, MT=64 (512 blocks = 2/CU)
    gemm_nt_lds<64, true><<<(E / 128) * (M / 64), 256, 0, stream>>>(
        wob, attn, bo, out, E, E, 1);
}

// Round 10
// 177.850 us; speedup vs baseline: 1.0686x; 1.0242x over previous
//
#include <hip/hip_runtime.h>

typedef __bf16 bf16_t;
typedef __attribute__((ext_vector_type(8))) __bf16 bf16x8;
typedef __attribute__((ext_vector_type(4))) __bf16 bf16x4;
typedef __attribute__((ext_vector_type(4))) float f32x4;
typedef __attribute__((ext_vector_type(16))) float f32x16;
typedef __attribute__((ext_vector_type(2))) unsigned uint2v;

#define MFMA16(a, b, c) __builtin_amdgcn_mfma_f32_16x16x32_bf16((a), (b), (c), 0, 0, 0)
#define MFMA32(a, b, c) __builtin_amdgcn_mfma_f32_32x32x16_bf16((a), (b), (c), 0, 0, 0)
#define LOG2E 1.44269504088896f

// Async global->LDS 16B copy. LDS dest is the WAVE-UNIFORM base; HW places
// lane i's 16B at base + 16*i. gptr is per-lane.
__device__ __forceinline__ void async16(const bf16_t* g, bf16_t* l) {
    __builtin_amdgcn_global_load_lds(
        (const __attribute__((address_space(1))) unsigned int*)g,
        (__attribute__((address_space(3))) unsigned int*)l, 16, 0, 0);
}

__device__ __forceinline__ unsigned pack2(float a, float b) {
    union { bf16_t e[2]; unsigned u; } x;
    x.e[0] = (bf16_t)a; x.e[1] = (bf16_t)b;
    return x.u;
}

// lane[i]<->lane[i+32] half exchange on the VALU pipe (v_permlane32_swap_b32).
__device__ __forceinline__ void pl32swap(unsigned& a, unsigned& b) {
    uint2v r = __builtin_amdgcn_permlane32_swap(a, b, false, false);
    a = r[0]; b = r[1];
}

// Raw workgroup barrier WITHOUT the vmcnt(0) drain of __syncthreads.
__device__ __forceinline__ void pbar() {
    asm volatile("" ::: "memory");
    __builtin_amdgcn_s_barrier();
    asm volatile("" ::: "memory");
}

// ---------------------------------------------------------------------------
// Fused fp32 -> bf16 conversion of x / W_in / W_out into contiguous ws region.
// ---------------------------------------------------------------------------
__global__ __launch_bounds__(256) void conv3(
    const float* __restrict__ s0, const float* __restrict__ s1,
    const float* __restrict__ s2, bf16_t* __restrict__ dst,
    int n0, int n1)
{
    const int i = (blockIdx.x * 256 + threadIdx.x) * 8;
    const float* src;
    int off;
    if (i < n0)           { src = s0; off = 0; }
    else if (i < n0 + n1) { src = s1; off = n0; }
    else                  { src = s2; off = n0 + n1; }
    const float4 a = *reinterpret_cast<const float4*>(src + i - off);
    const float4 b = *reinterpret_cast<const float4*>(src + i - off + 4);
    bf16x8 o;
    o[0] = (bf16_t)a.x; o[1] = (bf16_t)a.y; o[2] = (bf16_t)a.z; o[3] = (bf16_t)a.w;
    o[4] = (bf16_t)b.x; o[5] = (bf16_t)b.y; o[6] = (bf16_t)b.z; o[7] = (bf16_t)b.w;
    *reinterpret_cast<bf16x8*>(dst + i) = o;
}

// ---------------------------------------------------------------------------
// QKV projection GEMM -- 192(f) x 256(m) tile, BK=64, 8 waves, 4-phase
// quadrant schedule, 256 blocks = 1/CU (R8-verified: -5 us vs 2-phase).
// ---------------------------------------------------------------------------
__global__ __launch_bounds__(512, 2) void gemm_qkv(
    const bf16_t* __restrict__ W, const bf16_t* __restrict__ X,
    const float* __restrict__ bias, bf16_t* __restrict__ qkv,
    bf16_t* __restrict__ vtp)
{
    constexpr int K = 1024;
    constexpr int NSTEP = K / 64;        // 16
    constexpr int AELEM = 192 * 64;      // 12288 elems = 24 KB
    constexpr int BELEM = 256 * 64;      // 16384 elems = 32 KB

    __shared__ bf16_t lds[2][AELEM + BELEM];   // 112 KB total

    const int tid  = threadIdx.x;        // 0..511
    const int lane = tid & 63;
    const int wv   = tid >> 6;           // 0..7
    const int wm   = wv >> 2;            // f-half of 192 (96 rows each)
    const int wn   = wv & 3;             // m-quarter of 256 (64 rows each)
    const int l15  = lane & 15;
    const int qd   = lane >> 4;

    const int id = blockIdx.x;           // 0..255
    const int x8 = id & 7, k = id >> 3;  // k 0..31
    const int mb = ((k & 1) * 8 + x8) * 256;
    const int fb = (k >> 1) * 192;

    f32x4 acc[6][4] = {};                // [i: f frag 0..5][j: m frag 0..3]

    auto stage = [&](int set, int k0) {
        bf16_t* Ab = lds[set];
        bf16_t* Bb = lds[set] + AELEM;
#pragma unroll
        for (int t = 0; t < 3; t++) {    // A: 192 rows = 1536 chunks
            const int p = t * 512 + tid;
            const int r = p >> 3;
            const int c = (p & 7) ^ (r & 7);
            async16(W + (size_t)(fb + r) * K + k0 + c * 8,
                    Ab + (t * 512 + wv * 64) * 8);
        }
#pragma unroll
        for (int t = 0; t < 4; t++) {    // B: 256 rows = 2048 chunks
            const int p = t * 512 + tid;
            const int r = p >> 3;
            const int c = (p & 7) ^ (r & 7);
            async16(X + (size_t)(mb + r) * K + k0 + c * 8,
                    Bb + (t * 512 + wv * 64) * 8);
        }
    };

    stage(0, 0);                         // prologue: step 0 -> buf 0
    for (int s = 0; s < NSTEP; s++) {
        const int set = s & 1;
        __syncthreads();                 // buf[set] staging drained; fence
        if (s + 1 < NSTEP) stage(set ^ 1, (s + 1) * 64);

        const bf16_t* Ab = lds[set];
        const bf16_t* Bb = lds[set] + AELEM;

        bf16x8 a0[3][2], a1[3][2], b0[2][2], b1[2][2];

        // ---- phase 1: Q(0,0) -- load a0 (i=0..2), b0 (j=0..1) ----
#pragma unroll
        for (int i = 0; i < 3; i++) {
            const int r = wm * 96 + i * 16 + l15;
            a0[i][0] = *reinterpret_cast<const bf16x8*>(
                Ab + r * 64 + ((qd ^ (r & 7)) * 8));
            a0[i][1] = *reinterpret_cast<const bf16x8*>(
                Ab + r * 64 + (((4 + qd) ^ (r & 7)) * 8));
        }
#pragma unroll
        for (int j = 0; j < 2; j++) {
            const int r = wn * 64 + j * 16 + l15;
            b0[j][0] = *reinterpret_cast<const bf16x8*>(
                Bb + r * 64 + ((qd ^ (r & 7)) * 8));
            b0[j][1] = *reinterpret_cast<const bf16x8*>(
                Bb + r * 64 + (((4 + qd) ^ (r & 7)) * 8));
        }
        __builtin_amdgcn_s_setprio(1);
#pragma unroll
        for (int i = 0; i < 3; i++)
#pragma unroll
            for (int j = 0; j < 2; j++) {
                acc[i][j] = MFMA16(a0[i][0], b0[j][0], acc[i][j]);
                acc[i][j] = MFMA16(a0[i][1], b0[j][1], acc[i][j]);
            }
        __builtin_amdgcn_s_setprio(0);
        pbar();

        // ---- phase 2: Q(1,0) -- load a1 (i=3..5), reuse b0 ----
#pragma unroll
        for (int i = 0; i < 3; i++) {
            const int r = wm * 96 + (i + 3) * 16 + l15;
            a1[i][0] = *reinterpret_cast<const bf16x8*>(
                Ab + r * 64 + ((qd ^ (r & 7)) * 8));
            a1[i][1] = *reinterpret_cast<const bf16x8*>(
                Ab + r * 64 + (((4 + qd) ^ (r & 7)) * 8));
        }
        __builtin_amdgcn_s_setprio(1);
#pragma unroll
        for (int i = 0; i < 3; i++)
#pragma unroll
            for (int j = 0; j < 2; j++) {
                acc[i + 3][j] = MFMA16(a1[i][0], b0[j][0], acc[i + 3][j]);
                acc[i + 3][j] = MFMA16(a1[i][1], b0[j][1], acc[i + 3][j]);
            }
        __builtin_amdgcn_s_setprio(0);
        pbar();

        // ---- phase 3: Q(1,1) -- load b1 (j=2..3), reuse a1 ----
#pragma unroll
        for (int j = 0; j < 2; j++) {
            const int r = wn * 64 + (j + 2) * 16 + l15;
            b1[j][0] = *reinterpret_cast<const bf16x8*>(
                Bb + r * 64 + ((qd ^ (r & 7)) * 8));
            b1[j][1] = *reinterpret_cast<const bf16x8*>(
                Bb + r * 64 + (((4 + qd) ^ (r & 7)) * 8));
        }
        __builtin_amdgcn_s_setprio(1);
#pragma unroll
        for (int i = 0; i < 3; i++)
#pragma unroll
            for (int j = 0; j < 2; j++) {
                acc[i + 3][j + 2] = MFMA16(a1[i][0], b1[j][0], acc[i + 3][j + 2]);
                acc[i + 3][j + 2] = MFMA16(a1[i][1], b1[j][1], acc[i + 3][j + 2]);
            }
        __builtin_amdgcn_s_setprio(0);
        pbar();

        // ---- phase 4: Q(0,1) -- reuse a0, b1 (no reads) ----
        __builtin_amdgcn_s_setprio(1);
#pragma unroll
        for (int i = 0; i < 3; i++)
#pragma unroll
            for (int j = 0; j < 2; j++) {
                acc[i][j + 2] = MFMA16(a0[i][0], b1[j][0], acc[i][j + 2]);
                acc[i][j + 2] = MFMA16(a0[i][1], b1[j][1], acc[i][j + 2]);
            }
        __builtin_amdgcn_s_setprio(0);
    }

    // ---- epilogue: bias + per-i scale; V third transposed into vT ----
#pragma unroll
    for (int i = 0; i < 6; i++) {
        const int f0i = fb + wm * 96 + i * 16;       // 16-aligned group base
        const int f0  = f0i + qd * 4;
        const float scale = (f0i < 1024) ? 0.125f * LOG2E : 1.0f;
        const bool vblk = (f0i >= 2048);
        float bs[4];
#pragma unroll
        for (int r = 0; r < 4; r++) bs[r] = bias[f0 + r];
#pragma unroll
        for (int j = 0; j < 4; j++) {
            const int m = mb + wn * 64 + j * 16 + l15;
            if (vblk) {
                const int sIdx = m >> 1;          // B = 2 row interleave
                const int b2   = (m & 1) << 4;    // b*16
#pragma unroll
                for (int r = 0; r < 4; r++) {
                    const int fv = f0 + r - 2048;
                    vtp[(size_t)((b2 + (fv >> 6)) * 64 + (fv & 63)) * 2048 + sIdx] =
                        (bf16_t)(acc[i][j][r] + bs[r]);
                }
            } else {
                bf16x4 o;
#pragma unroll
                for (int r = 0; r < 4; r++)
                    o[r] = (bf16_t)((acc[i][j][r] + bs[r]) * scale);
                *reinterpret_cast<bf16x4*>(qkv + (size_t)m * 3072 + f0) = o;
            }
        }
    }
}

// ---------------------------------------------------------------------------
// Output projection GEMM -- 64(f) x 256(m) tile, BK=64, 8 waves, 2-sub-phase
// schedule (4-phase template adapted to f=1024: the f dimension only
// supports a 64-row tile at 256-block full subscription). Grid 16x16 = 256
// blocks = 1/CU. Waves 2(f)x4(m): per-wave 32f x 64m, acc[2][4].
// Per K-step: __syncthreads (drains prefetch issued a full step earlier),
// issue 5 async16 for step s+1, then {load a+b0; 8 MFMA; pbar; load b1;
// 8 MFMA}. Chunk-XOR c^(r&7) involution on staging source and frag reads.
// k-order per output element: chunk qd then 4+qd per 64-step, steps
// ascending == the replaced BK=32 kernel's order -> bit-identical output.
// ---------------------------------------------------------------------------
__global__ __launch_bounds__(512, 2) void gemm_out(
    const bf16_t* __restrict__ W, const bf16_t* __restrict__ X,
    const float* __restrict__ bias, float* __restrict__ out)
{
    constexpr int K = 1024;
    constexpr int NSTEP = K / 64;        // 16
    constexpr int AELEM = 64 * 64;       // 8 KB
    constexpr int BELEM = 256 * 64;      // 32 KB

    __shared__ bf16_t lds[2][AELEM + BELEM];   // 80 KB total

    const int tid  = threadIdx.x;        // 0..511
    const int lane = tid & 63;
    const int wv   = tid >> 6;           // 0..7
    const int wm   = wv >> 2;            // f-half (32 rows each)
    const int wn   = wv & 3;             // m-quarter (64 rows each)
    const int l15  = lane & 15;
    const int qd   = lane >> 4;

    const int id = blockIdx.x;           // 0..255
    const int x8 = id & 7, k = id >> 3;  // k 0..31
    const int mb = ((k & 1) * 8 + x8) * 256;
    const int fb = (k >> 1) * 64;

    f32x4 acc[2][4] = {};                // [i: f frag 0..1][j: m frag 0..3]

    auto stage = [&](int set, int k0) {
        bf16_t* Ab = lds[set];
        bf16_t* Bb = lds[set] + AELEM;
        {                                // A: 64 rows = 512 chunks (1/thread)
            const int p = tid;
            const int r = p >> 3;
            const int c = (p & 7) ^ (r & 7);
            async16(W + (size_t)(fb + r) * K + k0 + c * 8,
                    Ab + (wv * 64) * 8);
        }
#pragma unroll
        for (int t = 0; t < 4; t++) {    // B: 256 rows = 2048 chunks
            const int p = t * 512 + tid;
            const int r = p >> 3;
            const int c = (p & 7) ^ (r & 7);
            async16(X + (size_t)(mb + r) * K + k0 + c * 8,
                    Bb + (t * 512 + wv * 64) * 8);
        }
    };

    stage(0, 0);
    for (int s = 0; s < NSTEP; s++) {
        const int set = s & 1;
        __syncthreads();                 // buf[set] staging drained; fence
        if (s + 1 < NSTEP) stage(set ^ 1, (s + 1) * 64);

        const bf16_t* Ab = lds[set];
        const bf16_t* Bb = lds[set] + AELEM;

        bf16x8 a[2][2], b0[2][2], b1[2][2];

        // ---- sub-phase 1: all a + b-half 0 (j=0..1) ----
#pragma unroll
        for (int i = 0; i < 2; i++) {
            const int r = wm * 32 + i * 16 + l15;
            a[i][0] = *reinterpret_cast<const bf16x8*>(
                Ab + r * 64 + ((qd ^ (r & 7)) * 8));
            a[i][1] = *reinterpret_cast<const bf16x8*>(
                Ab + r * 64 + (((4 + qd) ^ (r & 7)) * 8));
        }
#pragma unroll
        for (int j = 0; j < 2; j++) {
            const int r = wn * 64 + j * 16 + l15;
            b0[j][0] = *reinterpret_cast<const bf16x8*>(
                Bb + r * 64 + ((qd ^ (r & 7)) * 8));
            b0[j][1] = *reinterpret_cast<const bf16x8*>(
                Bb + r * 64 + (((4 + qd) ^ (r & 7)) * 8));
        }
        __builtin_amdgcn_s_setprio(1);
#pragma unroll
        for (int i = 0; i < 2; i++)
#pragma unroll
            for (int j = 0; j < 2; j++) {
                acc[i][j] = MFMA16(a[i][0], b0[j][0], acc[i][j]);
                acc[i][j] = MFMA16(a[i][1], b0[j][1], acc[i][j]);
            }
        __builtin_amdgcn_s_setprio(0);
        pbar();

        // ---- sub-phase 2: b-half 1 (j=2..3), reuse a ----
#pragma unroll
        for (int j = 0; j < 2; j++) {
            const int r = wn * 64 + (j + 2) * 16 + l15;
            b1[j][0] = *reinterpret_cast<const bf16x8*>(
                Bb + r * 64 + ((qd ^ (r & 7)) * 8));
            b1[j][1] = *reinterpret_cast<const bf16x8*>(
                Bb + r * 64 + (((4 + qd) ^ (r & 7)) * 8));
        }
        __builtin_amdgcn_s_setprio(1);
#pragma unroll
        for (int i = 0; i < 2; i++)
#pragma unroll
            for (int j = 0; j < 2; j++) {
                acc[i][j + 2] = MFMA16(a[i][0], b1[j][0], acc[i][j + 2]);
                acc[i][j + 2] = MFMA16(a[i][1], b1[j][1], acc[i][j + 2]);
            }
        __builtin_amdgcn_s_setprio(0);
    }

    // ---- epilogue: bias, f32 stores ----
#pragma unroll
    for (int i = 0; i < 2; i++) {
        const int f0 = fb + wm * 32 + i * 16 + qd * 4;
        float bs[4];
#pragma unroll
        for (int r = 0; r < 4; r++) bs[r] = bias[f0 + r];
#pragma unroll
        for (int j = 0; j < 4; j++) {
            const int m = mb + wn * 64 + j * 16 + l15;
            float4 o;
            o.x = acc[i][j][0] + bs[0];
            o.y = acc[i][j][1] + bs[1];
            o.z = acc[i][j][2] + bs[2];
            o.w = acc[i][j][3] + bs[3];
            *reinterpret_cast<float4*>(out + (size_t)m * 1024 + f0) = o;
        }
    }
}

// ---------------------------------------------------------------------------
// Flash attention with IN-BLOCK KV-split x2 (exact R2 kernel, verified
// 54-55 us across R2/R6/R7/R8; the committed local optimum -- every
// perturbation of this decomposition lost: R1 waves, R3 blocks, R4/R9
// register P-lag pipelines, R5 V-direct). Block = 4 waves / 128 q.
// Grid 32 bh x 16 = 512 blocks, 2/CU.
// ---------------------------------------------------------------------------
__global__ __launch_bounds__(256, 2) void flash_attn(
    const bf16_t* __restrict__ qkv, const bf16_t* __restrict__ vT,
    bf16_t* __restrict__ attn, int S, int B)
{
    const int E3 = 3072, E = 1024;
    const int bh = blockIdx.x, b = bh >> 4, h = bh & 15;
    const int tid = threadIdx.x, lane = tid & 63, wv = tid >> 6;  // 0..3
    const int qw = wv & 1;               // q sub-block (64 q each)
    const int pr = wv >> 1;              // KV half
    const int l31 = lane & 31, half = lane >> 5;

    __shared__ bf16_t Kt[2][2][64 * 64];  // [pair][set]; chunk c at c^(r&7)
    __shared__ bf16_t Vt[2][2][64 * 64];  // [pair][set]; row d, chunk c at c^(d&7)
    __shared__ float  lsh[2][64];

    const int q0 = blockIdx.y * 128 + qw * 64;

    bf16x8 qf[2][4];                     // Q[q][k = ks*16 + half*8 + j]
#pragma unroll
    for (int qt = 0; qt < 2; qt++) {
        const bf16_t* qp = qkv + (size_t)((q0 + qt * 32 + l31) * B + b) * E3 + h * 64;
#pragma unroll
        for (int ks = 0; ks < 4; ks++)
            qf[qt][ks] = *reinterpret_cast<const bf16x8*>(qp + ks * 16 + half * 8);
    }

    f32x16 oacc[2][2] = {};              // [qt][d-tile]; row=d col=q
    float lrun[2] = {0.0f, 0.0f};

    auto stage = [&](int set, int kv) {
#pragma unroll
        for (int t = 0; t < 4; t++) {
            const int p = (qw * 4 + t) * 64 + lane;     // phys chunk 0..511
            const int r = p >> 3, cl = (p & 7) ^ (r & 7);
            async16(qkv + (size_t)((kv + r) * B + b) * E3 + E + h * 64 + cl * 8,
                    &Kt[pr][set][(qw * 4 + t) * 512]);
            async16(vT + (size_t)(bh * 64 + r) * 2048 + kv + cl * 8,
                    &Vt[pr][set][(qw * 4 + t) * 512]);
        }
    };

    const int kvbase = pr * (S / 2);
    const int NIT = S / 128;             // 16 iters of 64 per pair

    stage(0, kvbase);
    int set = 0;
    for (int it = 0; it < NIT; it++) {
        __syncthreads();                 // buf[set] ready; buf[set^1] free
        if (it + 1 < NIT) stage(set ^ 1, kvbase + (it + 1) * 64);

        const bf16_t* K_ = Kt[pr][set];
        const bf16_t* V_ = Vt[pr][set];

        union PF { unsigned u[4]; bf16x8 v; };
        PF pf[2][4];
#pragma unroll
        for (int nt = 0; nt < 2; nt++) {
            const int r = nt * 32 + l31;
            const int r7 = r & 7;
            bf16x8 kf[4];
#pragma unroll
            for (int ks = 0; ks < 4; ks++)
                kf[ks] = *reinterpret_cast<const bf16x8*>(
                    K_ + r * 64 + (((ks * 2 + half) ^ r7) * 8));
#pragma unroll
            for (int qt = 0; qt < 2; qt++) {
                f32x16 st = {};
                __builtin_amdgcn_s_setprio(1);
#pragma unroll
                for (int ks = 0; ks < 4; ks++)
                    st = MFMA32(kf[ks], qf[qt][ks], st);
                __builtin_amdgcn_s_setprio(0);
                float ls = 0.0f;
                unsigned q8[8];
#pragma unroll
                for (int g = 0; g < 4; g++) {
                    const float p0 = __builtin_amdgcn_exp2f(st[4 * g]);
                    const float p1 = __builtin_amdgcn_exp2f(st[4 * g + 1]);
                    const float p2 = __builtin_amdgcn_exp2f(st[4 * g + 2]);
                    const float p3 = __builtin_amdgcn_exp2f(st[4 * g + 3]);
                    ls += (p0 + p1) + (p2 + p3);
                    q8[2 * g]     = pack2(p0, p1);
                    q8[2 * g + 1] = pack2(p2, p3);
                }
                lrun[qt] += ls;
                pl32swap(q8[0], q8[2]); pl32swap(q8[1], q8[3]);
                pl32swap(q8[4], q8[6]); pl32swap(q8[5], q8[7]);
                pf[qt][nt * 2 + 0].u[0] = q8[0]; pf[qt][nt * 2 + 0].u[1] = q8[1];
                pf[qt][nt * 2 + 0].u[2] = q8[2]; pf[qt][nt * 2 + 0].u[3] = q8[3];
                pf[qt][nt * 2 + 1].u[0] = q8[4]; pf[qt][nt * 2 + 1].u[1] = q8[5];
                pf[qt][nt * 2 + 1].u[2] = q8[6]; pf[qt][nt * 2 + 1].u[3] = q8[7];
            }
        }
        __builtin_amdgcn_s_setprio(1);
#pragma unroll
        for (int kn = 0; kn < 4; kn++)
#pragma unroll
            for (int dt = 0; dt < 2; dt++) {
                const int d = dt * 32 + l31;
                bf16x8 vf = *reinterpret_cast<const bf16x8*>(
                    V_ + d * 64 + (((kn * 2 + half) ^ (d & 7)) * 8));
                oacc[0][dt] = MFMA32(vf, pf[0][kn].v, oacc[0][dt]);
                oacc[1][dt] = MFMA32(vf, pf[1][kn].v, oacc[1][dt]);
            }
        __builtin_amdgcn_s_setprio(0);
        set ^= 1;
    }

    // --- Epilogue: merge the two KV halves through LDS, normalize, store ---
    __syncthreads();                     // all K/V reads done; LDS reusable
    float lr[2];
#pragma unroll
    for (int qt = 0; qt < 2; qt++) lr[qt] = lrun[qt] + __shfl_xor(lrun[qt], 32);

    // fp32 scratch overlays Kt (32 KB = 2 regions x 64q x 64d), d-major
    float* fo = reinterpret_cast<float*>(&Kt[0][0][0]) + qw * 4096;

    if (pr == 1) {
#pragma unroll
        for (int qt = 0; qt < 2; qt++) {
            const int ql = qt * 32 + l31;
            lsh[qw][ql] = lr[qt];        // both halves write same value
#pragma unroll
            for (int dt = 0; dt < 2; dt++)
#pragma unroll
                for (int g = 0; g < 4; g++)
#pragma unroll
                    for (int r = 0; r < 4; r++) {
                        const int d = dt * 32 + g * 8 + half * 4 + r;
                        fo[d * 64 + ql] = oacc[qt][dt][4 * g + r];
                    }
        }
    }
    __syncthreads();
    if (pr == 0) {
#pragma unroll
        for (int qt = 0; qt < 2; qt++) {
            const int ql = qt * 32 + l31;
            const float inv = 1.0f / (lr[qt] + lsh[qw][ql]);
            const int qrow = q0 + qt * 32 + l31;
#pragma unroll
            for (int dt = 0; dt < 2; dt++)
#pragma unroll
                for (int g = 0; g < 4; g++) {
                    bf16x4 o;
#pragma unroll
                    for (int r = 0; r < 4; r++) {
                        const int d = dt * 32 + g * 8 + half * 4 + r;
                        o[r] = (bf16_t)((oacc[qt][dt][4 * g + r] + fo[d * 64 + ql]) * inv);
                    }
                    *reinterpret_cast<bf16x4*>(attn + (size_t)(qrow * B + b) * E +
                                               h * 64 + dt * 32 + g * 8 + half * 4) = o;
                }
        }
    }
}

extern "C" void kernel_launch(void* const* d_in, const int* in_sizes, int n_in,
                              void* d_out, int out_size, void* d_ws, size_t ws_size,
                              hipStream_t stream) {
    const float* x  = (const float*)d_in[0];
    const float* wi = (const float*)d_in[1];
    const float* bi = (const float*)d_in[2];
    const float* wo = (const float*)d_in[3];
    const float* bo = (const float*)d_in[4];
    float* out = (float*)d_out;

    const int S = 2048, B = 2, E = 1024;
    const int M = S * B;

    // Workspace layout:
    //   xb [M,1024] bf16  -- X in bf16; dead after QKV GEMM
    //   wib[3072,1024]    -- W_in bf16
    //   wob[1024,1024]    -- W_out bf16
    //   qkv[M,3072]       -- Q,K written by GEMM; V third left unwritten
    //   vT [32][64][2048] -- V transposed, written by the GEMM epilogue
    //   attn = xb overlay -- flash output (xb dead by then)
    bf16_t* xb   = (bf16_t*)d_ws;
    bf16_t* wib  = xb  + (size_t)M * E;
    bf16_t* wob  = wib + (size_t)3 * E * E;
    bf16_t* qkv  = wob + (size_t)E * E;
    bf16_t* vT   = qkv + (size_t)M * 3 * E;
    bf16_t* attn = xb;

    // 0) fused fp32 -> bf16
    const int n0 = M * E, n1 = 3 * E * E, n2 = E * E;
    conv3<<<(n0 + n1 + n2) / 8 / 256, 256, 0, stream>>>(x, wi, wo, xb, n0, n1);

    // 1) QKV projection: 192x256 4-phase template, 256 blocks = 1/CU;
    //    V third transposed into vT; qscale folded into q.
    gemm_qkv<<<256, 512, 0, stream>>>(wib, xb, bi, qkv, vT);

    // 2) Flash attention (exact R2 kernel; attn overlays dead xb)
    flash_attn<<<dim3(B * 16, S / 128), 256, 0, stream>>>(qkv, vT, attn, S, B);

    // 3) Output projection: 64x256 phased template, 256 blocks = 1/CU
    gemm_out<<<256, 512, 0, stream>>>(wob, attn, bo, out);
}